// Round 2
// baseline (4248.266 us; speedup 1.0000x reference)
//
#include <hip/hip_runtime.h>

#define N_   16384
#define D_   256
#define E_   262144
#define ET_  278528   // E_ + N_ (self loops)
#define DI_  512

static __device__ __forceinline__ float wave_sum(float v){
#pragma unroll
  for (int m = 1; m < 64; m <<= 1) v += __shfl_xor(v, m);
  return v;
}
static __device__ __forceinline__ float wave_max(float v){
#pragma unroll
  for (int m = 1; m < 64; m <<= 1) v = fmaxf(v, __shfl_xor(v, m));
  return v;
}
static __device__ __forceinline__ float silu_f(float x){ return x / (1.f + __expf(-x)); }

// ---------------------------------------------------------------- diagnostic marker (fires only if ws too small)
__global__ __launch_bounds__(256) void marker_kernel(float* __restrict__ out){
  out[threadIdx.x] = 1e9f;
}

// ---------------------------------------------------------------- permute x (3,N,256) -> xcat (N,768)
__global__ __launch_bounds__(256) void permute_kernel(const float* __restrict__ x, float* __restrict__ xcat){
  int idx = blockIdx.x * 256 + threadIdx.x;      // over 3*16384*64 float4
  if (idx >= 3 * N_ * 64) return;
  int d4  = idx & 63;
  int n   = (idx >> 6) & (N_ - 1);
  int hop = idx >> 20;
  float4 v = ((const float4*)x)[((size_t)hop << 20) + ((size_t)n << 6) + d4];
  ((float4*)xcat)[(size_t)n * 192 + hop * 64 + d4] = v;
}

// ---------------------------------------------------------------- generic fp32 GEMM  C[row_map[m], c_off+n] = A(MxK)B(KxN) + bias
__global__ __launch_bounds__(256) void sgemm_kernel(
    const float* __restrict__ A, int lda,
    const float* __restrict__ B, int ldb, int N,
    float* __restrict__ C, int ldc, int c_off,
    const float* __restrict__ bias,
    const int* __restrict__ row_map, int K)
{
  __shared__ float As[16][68];
  __shared__ float Bs[16][68];
  const int tid = threadIdx.x;
  const int tx = tid & 15;
  const int ty = tid >> 4;
  const int m0 = blockIdx.x * 64;
  const int n0 = blockIdx.y * 64;
  const int ar = tid >> 2;
  const int ac = (tid & 3) << 2;
  const int br = tid >> 4;
  const int bc = (tid & 15) << 2;
  const bool vecB = ((ldb & 3) == 0);
  float acc[4][4] = {};
  for (int k0 = 0; k0 < K; k0 += 16) {
    float4 av = *reinterpret_cast<const float4*>(&A[(size_t)(m0 + ar) * lda + k0 + ac]);
    As[ac + 0][ar] = av.x; As[ac + 1][ar] = av.y; As[ac + 2][ar] = av.z; As[ac + 3][ar] = av.w;
    float4 bv;
    if (vecB && (n0 + bc + 3 < N)) {
      bv = *reinterpret_cast<const float4*>(&B[(size_t)(k0 + br) * ldb + n0 + bc]);
    } else {
      bv.x = (n0 + bc + 0 < N) ? B[(size_t)(k0 + br) * ldb + n0 + bc + 0] : 0.f;
      bv.y = (n0 + bc + 1 < N) ? B[(size_t)(k0 + br) * ldb + n0 + bc + 1] : 0.f;
      bv.z = (n0 + bc + 2 < N) ? B[(size_t)(k0 + br) * ldb + n0 + bc + 2] : 0.f;
      bv.w = (n0 + bc + 3 < N) ? B[(size_t)(k0 + br) * ldb + n0 + bc + 3] : 0.f;
    }
    Bs[br][bc + 0] = bv.x; Bs[br][bc + 1] = bv.y; Bs[br][bc + 2] = bv.z; Bs[br][bc + 3] = bv.w;
    __syncthreads();
#pragma unroll
    for (int k = 0; k < 16; ++k) {
      float a[4], b[4];
      *(float4*)a = *reinterpret_cast<const float4*>(&As[k][ty << 2]);
      *(float4*)b = *reinterpret_cast<const float4*>(&Bs[k][tx << 2]);
#pragma unroll
      for (int i = 0; i < 4; ++i)
#pragma unroll
        for (int j = 0; j < 4; ++j) acc[i][j] = fmaf(a[i], b[j], acc[i][j]);
    }
    __syncthreads();
  }
#pragma unroll
  for (int i = 0; i < 4; ++i) {
    int m = m0 + (ty << 2) + i;
    int row = row_map ? row_map[m] : m;
    float* Crow = C + (size_t)row * ldc + c_off;
#pragma unroll
    for (int j = 0; j < 4; ++j) {
      int n = n0 + (tx << 2) + j;
      if (n < N) Crow[n] = acc[i][j] + (bias ? bias[n] : 0.f);
    }
  }
}

// ---------------------------------------------------------------- rowwise LN(256) + silu, in place
__global__ __launch_bounds__(256) void ln_silu_kernel(float* __restrict__ x, const float* __restrict__ g, const float* __restrict__ b){
  __shared__ float red[4];
  const int row = blockIdx.x; const int t = threadIdx.x;
  float v = x[(size_t)row * 256 + t];
  float sv = wave_sum(v);
  if ((t & 63) == 0) red[t >> 6] = sv;
  __syncthreads();
  float mean = (red[0] + red[1] + red[2] + red[3]) * (1.f / 256.f);
  __syncthreads();
  float dv = v - mean;
  float sq = wave_sum(dv * dv);
  if ((t & 63) == 0) red[t >> 6] = sq;
  __syncthreads();
  float var = (red[0] + red[1] + red[2] + red[3]) * (1.f / 256.f);
  float o = dv * rsqrtf(var + 1e-5f) * g[t] + b[t];
  x[(size_t)row * 256 + t] = silu_f(o);
}

// ---------------------------------------------------------------- per-node attention logits
__global__ __launch_bounds__(256) void att_scores_kernel(const float* __restrict__ h, const float* __restrict__ asr,
                                                         const float* __restrict__ adt, float* __restrict__ as_, float* __restrict__ ad_){
  int wid = threadIdx.x >> 6, lane = threadIdx.x & 63;
  int n = blockIdx.x * 4 + wid;
  float s1 = 0.f, s2 = 0.f;
  for (int f = lane; f < 256; f += 64) {
    float hv = h[(size_t)n * 256 + f];
    s1 = fmaf(hv, asr[f], s1); s2 = fmaf(hv, adt[f], s2);
  }
  s1 = wave_sum(s1); s2 = wave_sum(s2);
  if (lane == 0) { as_[n] = s1; ad_[n] = s2; }
}

// ---------------------------------------------------------------- CSR build
__global__ __launch_bounds__(256) void count_kernel(const int* __restrict__ ei, int* __restrict__ cnt_in, int* __restrict__ deg_out){
  int i = blockIdx.x * 256 + threadIdx.x;
  if (i >= ET_) return;
  int dst = (i < E_) ? ei[E_ + i] : (i - E_);
  atomicAdd(&cnt_in[dst], 1);
  if (i < E_) atomicAdd(&deg_out[ei[i]], 1);
}

__global__ __launch_bounds__(1024) void scan_offsets_kernel(const int* __restrict__ cnt, int* __restrict__ off, int* __restrict__ cursor){
  __shared__ int part[1024];
  int t = threadIdx.x;
  int base = t * 16;
  int local[16]; int s = 0;
#pragma unroll
  for (int i = 0; i < 16; ++i) { local[i] = s; s += cnt[base + i]; }
  part[t] = s; __syncthreads();
  for (int d = 1; d < 1024; d <<= 1) {
    int val = part[t];
    int add = (t >= d) ? part[t - d] : 0;
    __syncthreads();
    part[t] = val + add;
    __syncthreads();
  }
  int prev = (t > 0) ? part[t - 1] : 0;
#pragma unroll
  for (int i = 0; i < 16; ++i) { int o = prev + local[i]; off[base + i] = o; cursor[base + i] = o; }
  if (t == 1023) off[N_] = part[1023];
}

__global__ __launch_bounds__(256) void scatter_kernel(const int* __restrict__ ei, int* __restrict__ cursor, int* __restrict__ csr){
  int i = blockIdx.x * 256 + threadIdx.x;
  if (i >= ET_) return;
  int dst = (i < E_) ? ei[E_ + i] : (i - E_);
  int pos = atomicAdd(&cursor[dst], 1);
  csr[pos] = i;
}

// ---------------------------------------------------------------- GAT softmax + aggregate (gather, no float atomics). writes cat[:, :256]
__global__ __launch_bounds__(256) void gat_agg_kernel(const int* __restrict__ ei, const int* __restrict__ off, const int* __restrict__ csr,
                                                      const float* __restrict__ as_, const float* __restrict__ ad_,
                                                      const float* __restrict__ h, const float* __restrict__ gat_b, float* __restrict__ cat){
  const int dst = blockIdx.x;
  const int t = threadIdx.x;
  const int o0 = off[dst];
  int deg = off[dst + 1] - o0;
  if (deg > 1024) deg = 1024;   // cannot occur (mean deg ~17); guards LDS
  __shared__ int   ssrc[1024];
  __shared__ float se[1024];
  __shared__ float red[4];
  const float adv = ad_[dst];
  float m = -1e30f;
  for (int j = t; j < deg; j += 256) {
    int eid = csr[o0 + j];
    int src = (eid < E_) ? ei[eid] : (eid - E_);
    float e = as_[src] + adv;
    e = (e >= 0.f) ? e : 0.2f * e;
    ssrc[j] = src; se[j] = e;
    m = fmaxf(m, e);
  }
  m = wave_max(m);
  if ((t & 63) == 0) red[t >> 6] = m;
  __syncthreads();
  m = fmaxf(fmaxf(red[0], red[1]), fmaxf(red[2], red[3]));
  __syncthreads();
  float dsum = 0.f;
  for (int j = t; j < deg; j += 256) { float x = __expf(se[j] - m); se[j] = x; dsum += x; }
  dsum = wave_sum(dsum);
  if ((t & 63) == 0) red[t >> 6] = dsum;
  __syncthreads();
  float inv = 1.f / (red[0] + red[1] + red[2] + red[3]);
  float acc = gat_b[t];
  for (int j = 0; j < deg; ++j) acc = fmaf(se[j] * inv, h[(size_t)ssrc[j] * 256 + t], acc);
  cat[(size_t)dst * 512 + t] = acc;
}

// ---------------------------------------------------------------- sort key: (enc32(deg + noise*0.1) << 32) | idx
// __fmul_rn/__fadd_rn: forbid FMA contraction so rounding bit-matches the
// reference's separate mul-then-add (near-tie keys decide the mamba ordering).
__global__ __launch_bounds__(256) void key_kernel(const int* __restrict__ degO, const float* __restrict__ noise, unsigned long long* __restrict__ keys){
  int n = blockIdx.x * 256 + threadIdx.x;
  if (n >= N_) return;
  float k = __fadd_rn((float)degO[n], __fmul_rn(noise[n], 0.1f));
  unsigned u = __float_as_uint(k);
  u = (u & 0x80000000u) ? ~u : (u | 0x80000000u);
  keys[n] = ((unsigned long long)u << 32) | (unsigned)n;
}

// ---------------------------------------------------------------- single-block bitonic sort of 16384 u64 keys (== stable argsort)
__global__ __launch_bounds__(1024) void bitonic_kernel(const unsigned long long* __restrict__ keys, int* __restrict__ sidx){
  __shared__ unsigned long long s[N_];
  for (int i = threadIdx.x; i < N_; i += 1024) s[i] = keys[i];
  __syncthreads();
  for (int k = 2; k <= N_; k <<= 1) {
    for (int j = k >> 1; j > 0; j >>= 1) {
      for (int t = threadIdx.x; t < N_ / 2; t += 1024) {
        int i = 2 * t - (t & (j - 1));
        int ixj = i ^ j;
        bool up = ((i & k) == 0);
        unsigned long long a = s[i], b = s[ixj];
        if ((a > b) == up) { s[i] = b; s[ixj] = a; }
      }
      __syncthreads();
    }
  }
  for (int i = threadIdx.x; i < N_; i += 1024) sidx[i] = (int)(s[i] & 0xffffffffu);
}

// ---------------------------------------------------------------- u0 = xf[sidx]
__global__ __launch_bounds__(64) void gather_kernel(const float* __restrict__ xf, const int* __restrict__ sidx, float* __restrict__ u0){
  int i = blockIdx.x, t = threadIdx.x;
  ((float4*)u0)[(size_t)i * 64 + t] = ((const float4*)xf)[(size_t)sidx[i] * 64 + t];
}

// ---------------------------------------------------------------- causal depthwise conv (k=4) + silu; in = xz[:, :512] (stride 1024)
__global__ __launch_bounds__(256) void conv_silu_kernel(const float* __restrict__ xz, const float* __restrict__ cw, float* __restrict__ xm){
  int idx = blockIdx.x * 256 + threadIdx.x;
  if (idx >= N_ * DI_) return;
  int n = idx >> 9, c = idx & 511;
  float acc = 0.f;
#pragma unroll
  for (int k = 0; k < 4; ++k) {
    int nn = n - 3 + k;
    if (nn >= 0) acc = fmaf(xz[(size_t)nn * 1024 + c], cw[c * 4 + k], acc);
  }
  xm[idx] = silu_f(acc);
}

// ---------------------------------------------------------------- selective scan: thread=(d,s); dt fused (softplus) from xdbl col 0.
// writes ys into xz[:, :512] (row stride 1024)
__global__ __launch_bounds__(256) void scan_kernel(const float* __restrict__ xdbl, const float* __restrict__ dt_w,
                                                   const float* __restrict__ dt_b, const float* __restrict__ A_log,
                                                   float* __restrict__ ys){
  const int dl = threadIdx.x >> 4;
  const int s  = threadIdx.x & 15;
  const int d  = blockIdx.x * 16 + dl;
  const float Ac = -__expf(A_log[d * 16 + s]);
  __shared__ float sdt[64][16];
  __shared__ float sB[64][16];
  const int lr = threadIdx.x >> 4;   // row-in-chunk base
  const int lc = threadIdx.x & 15;   // col
  const int dbase = blockIdx.x * 16 + lc;
  const float dwv = dt_w[dbase];
  const float dbv = dt_b[dbase];
  float rdt[4], rB[4];
  auto issue = [&](int n0){
#pragma unroll
    for (int p = 0; p < 4; ++p) {
      int n = n0 + lr + p * 16;
      float x0 = xdbl[(size_t)n * 17];
      float v = fmaf(x0, dwv, dbv);
      rdt[p] = fmaxf(v, 0.f) + log1pf(__expf(-fabsf(v)));   // softplus
      rB[p]  = xdbl[(size_t)n * 17 + 1 + lc];
    }
  };
  auto commit = [&](){
#pragma unroll
    for (int p = 0; p < 4; ++p) { sdt[lr + p * 16][lc] = rdt[p]; sB[lr + p * 16][lc] = rB[p]; }
  };
  issue(0); commit(); __syncthreads();
  float h = 0.f;
  for (int c0 = 0; c0 < N_; c0 += 64) {
    const bool more = (c0 + 64) < N_;
    if (more) issue(c0 + 64);
#pragma unroll 4
    for (int i = 0; i < 64; ++i) {
      float dtv = sdt[i][dl];
      float Bv  = sB[i][s];
      h = fmaf(__expf(Ac * dtv), h, dtv * Bv);
      float p = h * Bv;
      p += __shfl_xor(p, 1); p += __shfl_xor(p, 2); p += __shfl_xor(p, 4); p += __shfl_xor(p, 8);
      if (s == 0) ys[(size_t)(c0 + i) * 1024 + d] = p;
    }
    __syncthreads();
    if (more) commit();
    __syncthreads();
  }
}

// ---------------------------------------------------------------- y = (ys + xm*D) * silu(zgate); ys & zgate live in xz, in place
__global__ __launch_bounds__(256) void ymod_kernel(float* __restrict__ xz, const float* __restrict__ xm,
                                                   const float* __restrict__ Dp){
  int idx = blockIdx.x * 256 + threadIdx.x;
  if (idx >= N_ * DI_) return;
  int n = idx >> 9, c = idx & 511;
  float yv = fmaf(xm[idx], Dp[c], xz[(size_t)n * 1024 + c]);
  float z = xz[(size_t)n * 1024 + 512 + c];
  xz[(size_t)n * 1024 + c] = yv * silu_f(z);
}

// ================================================================ host
extern "C" void kernel_launch(void* const* d_in, const int* in_sizes, int n_in,
                              void* d_out, int out_size, void* d_ws, size_t ws_size,
                              hipStream_t stream)
{
  (void)in_sizes; (void)n_in; (void)out_size;
  const float* x         = (const float*)d_in[0];
  const int*   ei        = (const int*)d_in[1];
  const float* pnoise    = (const float*)d_in[2];
  const float* hop_w     = (const float*)d_in[3];
  const float* hop_b     = (const float*)d_in[4];
  const float* hop_ln_g  = (const float*)d_in[5];
  const float* hop_ln_b  = (const float*)d_in[6];
  const float* gat_w     = (const float*)d_in[7];
  const float* att_src   = (const float*)d_in[8];
  const float* att_dst   = (const float*)d_in[9];
  const float* gat_b     = (const float*)d_in[10];
  const float* in_proj_w = (const float*)d_in[11];
  const float* conv_w    = (const float*)d_in[12];
  const float* x_proj_w  = (const float*)d_in[13];
  const float* dt_w      = (const float*)d_in[14];
  const float* dt_b      = (const float*)d_in[15];
  const float* A_log     = (const float*)d_in[16];
  const float* D_param   = (const float*)d_in[17];
  const float* out_w     = (const float*)d_in[18];
  const float* out_b     = (const float*)d_in[19];
  const float* mlp_w1    = (const float*)d_in[20];
  const float* mlp_b1    = (const float*)d_in[21];
  const float* mlp_ln_g  = (const float*)d_in[22];
  const float* mlp_ln_b  = (const float*)d_in[23];
  const float* mlp_w2    = (const float*)d_in[24];
  const float* mlp_b2    = (const float*)d_in[25];
  float* out = (float*)d_out;

  char* w = (char*)d_ws;
  auto alloc = [&](size_t bytes) -> void* {
    void* p = (void*)w; w += (bytes + 255) & ~(size_t)255; return p;
  };
  // Aliasing plan:
  //   xz  : xcat(N x 768) -> in_proj out(N x 1024); cols[:512] become ys then y
  //   xf  : xf -> mlp1 (xf dead after gather)
  //   h   : h  -> u0   (h dead after gat_agg)
  float* xz   = (float*)alloc((size_t)N_ * 1024 * 4);  // 64 MiB
  float* xf   = (float*)alloc((size_t)N_ * 256 * 4);   // 16 MiB
  float* h    = (float*)alloc((size_t)N_ * 256 * 4);   // 16 MiB
  float* xm   = (float*)alloc((size_t)N_ * 512 * 4);   // 32 MiB
  float* cat  = (float*)alloc((size_t)N_ * 512 * 4);   // 32 MiB
  float* xdbl = (float*)alloc((size_t)N_ * 17 * 4);
  float* as_  = (float*)alloc((size_t)N_ * 4);
  float* ad_  = (float*)alloc((size_t)N_ * 4);
  int* cnt    = (int*)alloc((size_t)N_ * 4);    // cnt & degO contiguous for one memset
  int* degO   = (int*)alloc((size_t)N_ * 4);
  int* cursor = (int*)alloc((size_t)N_ * 4);
  int* off    = (int*)alloc((size_t)(N_ + 1) * 4);
  int* sidx   = (int*)alloc((size_t)N_ * 4);
  int* csr    = (int*)alloc((size_t)ET_ * 4);
  unsigned long long* keys = (unsigned long long*)alloc((size_t)N_ * 8);
  float* u0   = h;     // alias
  float* mlp1 = xf;    // alias
  size_t needed = (size_t)(w - (char*)d_ws);
  if (needed > ws_size) {                    // diagnostic: absmax ~1e9 => ws too small
    marker_kernel<<<1, 256, 0, stream>>>(out);
    return;
  }

  hipMemsetAsync(cnt, 0, 2 * (size_t)N_ * 4, stream);

  // 1. xcat = permute(x)
  permute_kernel<<<(3 * N_ * 64) / 256, 256, 0, stream>>>(x, xz);
  // 2. xf = silu(LN(xcat @ hop_w + hop_b))
  sgemm_kernel<<<dim3(N_ / 64, 4), 256, 0, stream>>>(xz, 768, hop_w, 256, 256, xf, 256, 0, hop_b, nullptr, 768);
  ln_silu_kernel<<<N_, 256, 0, stream>>>(xf, hop_ln_g, hop_ln_b);
  // 3. h = xf @ gat_w
  sgemm_kernel<<<dim3(N_ / 64, 4), 256, 0, stream>>>(xf, 256, gat_w, 256, 256, h, 256, 0, nullptr, nullptr, 256);
  // 4. attention logits per node
  att_scores_kernel<<<N_ / 4, 256, 0, stream>>>(h, att_src, att_dst, as_, ad_);
  // 5. CSR by dst (incl self loops) + out-degree
  count_kernel<<<(ET_ + 255) / 256, 256, 0, stream>>>(ei, cnt, degO);
  scan_offsets_kernel<<<1, 1024, 0, stream>>>(cnt, off, cursor);
  scatter_kernel<<<(ET_ + 255) / 256, 256, 0, stream>>>(ei, cursor, csr);
  // 6. GAT softmax+aggregate -> cat[:, :256]
  gat_agg_kernel<<<N_, 256, 0, stream>>>(ei, off, csr, as_, ad_, h, gat_b, cat);
  // 7. stable argsort(deg + noise*0.1)
  key_kernel<<<N_ / 256, 256, 0, stream>>>(degO, pnoise, keys);
  bitonic_kernel<<<1, 1024, 0, stream>>>(keys, sidx);
  // 8. u0 = xf[sidx]; xz = u0 @ in_proj_w   (overwrites xcat; h dead -> u0)
  gather_kernel<<<N_, 64, 0, stream>>>(xf, sidx, u0);
  sgemm_kernel<<<dim3(N_ / 64, 16), 256, 0, stream>>>(u0, 256, in_proj_w, 1024, 1024, xz, 1024, 0, nullptr, nullptr, 256);
  // 9. depthwise causal conv + silu -> xm
  conv_silu_kernel<<<(N_ * DI_) / 256, 256, 0, stream>>>(xz, conv_w, xm);
  // 10. x_dbl = xm @ x_proj_w (N=17)
  sgemm_kernel<<<dim3(N_ / 64, 1), 256, 0, stream>>>(xm, 512, x_proj_w, 17, 17, xdbl, 17, 0, nullptr, nullptr, 512);
  // 11+12. selective scan (dt fused) -> ys = xz[:, :512]
  scan_kernel<<<DI_ / 16, 256, 0, stream>>>(xdbl, dt_w, dt_b, A_log, xz);
  // 13. y = (ys + xm*D) * silu(zgate), in place in xz[:, :512]
  ymod_kernel<<<(N_ * DI_) / 256, 256, 0, stream>>>(xz, xm, D_param);
  // 14. x_mamba = y @ out_w + out_b, scattered (un-permuted) into cat[:, 256:]
  sgemm_kernel<<<dim3(N_ / 64, 4), 256, 0, stream>>>(xz, 1024, out_w, 256, 256, cat, 512, 256, out_b, sidx, 512);
  // 15. MLP
  sgemm_kernel<<<dim3(N_ / 64, 4), 256, 0, stream>>>(cat, 512, mlp_w1, 256, 256, mlp1, 256, 0, mlp_b1, nullptr, 512);
  ln_silu_kernel<<<N_, 256, 0, stream>>>(mlp1, mlp_ln_g, mlp_ln_b);
  sgemm_kernel<<<dim3(N_ / 64, 4), 256, 0, stream>>>(mlp1, 256, mlp_w2, 256, 256, out, 256, 0, mlp_b2, nullptr, 256);
}

// Round 3
// 995.884 us; speedup vs baseline: 4.2658x; 4.2658x over previous
//
#include <hip/hip_runtime.h>

#define N_   16384
#define D_   256
#define E_   262144
#define ET_  278528   // E_ + N_ (self loops)
#define DI_  512
#define CH_  128      // scan chunks
#define CL_  128      // chunk length (CH_*CL_ == N_)

static __device__ __forceinline__ float wave_sum(float v){
#pragma unroll
  for (int m = 1; m < 64; m <<= 1) v += __shfl_xor(v, m);
  return v;
}
static __device__ __forceinline__ float wave_max(float v){
#pragma unroll
  for (int m = 1; m < 64; m <<= 1) v = fmaxf(v, __shfl_xor(v, m));
  return v;
}
static __device__ __forceinline__ float silu_f(float x){ return x / (1.f + __expf(-x)); }

// ---------------------------------------------------------------- diagnostic marker (fires only if ws too small)
__global__ __launch_bounds__(256) void marker_kernel(float* __restrict__ out){
  out[threadIdx.x] = 1e9f;
}

// ---------------------------------------------------------------- permute x (3,N,256) -> xcat (N,768)
__global__ __launch_bounds__(256) void permute_kernel(const float* __restrict__ x, float* __restrict__ xcat){
  int idx = blockIdx.x * 256 + threadIdx.x;      // over 3*16384*64 float4
  if (idx >= 3 * N_ * 64) return;
  int d4  = idx & 63;
  int n   = (idx >> 6) & (N_ - 1);
  int hop = idx >> 20;
  float4 v = ((const float4*)x)[((size_t)hop << 20) + ((size_t)n << 6) + d4];
  ((float4*)xcat)[(size_t)n * 192 + hop * 64 + d4] = v;
}

// ---------------------------------------------------------------- generic fp32 GEMM  C[row_map[m], c_off+n] = A(MxK)B(KxN) + bias
__global__ __launch_bounds__(256) void sgemm_kernel(
    const float* __restrict__ A, int lda,
    const float* __restrict__ B, int ldb, int N,
    float* __restrict__ C, int ldc, int c_off,
    const float* __restrict__ bias,
    const int* __restrict__ row_map, int K)
{
  __shared__ float As[16][68];
  __shared__ float Bs[16][68];
  const int tid = threadIdx.x;
  const int tx = tid & 15;
  const int ty = tid >> 4;
  const int m0 = blockIdx.x * 64;
  const int n0 = blockIdx.y * 64;
  const int ar = tid >> 2;
  const int ac = (tid & 3) << 2;
  const int br = tid >> 4;
  const int bc = (tid & 15) << 2;
  const bool vecB = ((ldb & 3) == 0);
  float acc[4][4] = {};
  for (int k0 = 0; k0 < K; k0 += 16) {
    float4 av = *reinterpret_cast<const float4*>(&A[(size_t)(m0 + ar) * lda + k0 + ac]);
    As[ac + 0][ar] = av.x; As[ac + 1][ar] = av.y; As[ac + 2][ar] = av.z; As[ac + 3][ar] = av.w;
    float4 bv;
    if (vecB && (n0 + bc + 3 < N)) {
      bv = *reinterpret_cast<const float4*>(&B[(size_t)(k0 + br) * ldb + n0 + bc]);
    } else {
      bv.x = (n0 + bc + 0 < N) ? B[(size_t)(k0 + br) * ldb + n0 + bc + 0] : 0.f;
      bv.y = (n0 + bc + 1 < N) ? B[(size_t)(k0 + br) * ldb + n0 + bc + 1] : 0.f;
      bv.z = (n0 + bc + 2 < N) ? B[(size_t)(k0 + br) * ldb + n0 + bc + 2] : 0.f;
      bv.w = (n0 + bc + 3 < N) ? B[(size_t)(k0 + br) * ldb + n0 + bc + 3] : 0.f;
    }
    Bs[br][bc + 0] = bv.x; Bs[br][bc + 1] = bv.y; Bs[br][bc + 2] = bv.z; Bs[br][bc + 3] = bv.w;
    __syncthreads();
#pragma unroll
    for (int k = 0; k < 16; ++k) {
      float a[4], b[4];
      *(float4*)a = *reinterpret_cast<const float4*>(&As[k][ty << 2]);
      *(float4*)b = *reinterpret_cast<const float4*>(&Bs[k][tx << 2]);
#pragma unroll
      for (int i = 0; i < 4; ++i)
#pragma unroll
        for (int j = 0; j < 4; ++j) acc[i][j] = fmaf(a[i], b[j], acc[i][j]);
    }
    __syncthreads();
  }
#pragma unroll
  for (int i = 0; i < 4; ++i) {
    int m = m0 + (ty << 2) + i;
    int row = row_map ? row_map[m] : m;
    float* Crow = C + (size_t)row * ldc + c_off;
#pragma unroll
    for (int j = 0; j < 4; ++j) {
      int n = n0 + (tx << 2) + j;
      if (n < N) Crow[n] = acc[i][j] + (bias ? bias[n] : 0.f);
    }
  }
}

// ---------------------------------------------------------------- rowwise LN(256) + silu, in place
__global__ __launch_bounds__(256) void ln_silu_kernel(float* __restrict__ x, const float* __restrict__ g, const float* __restrict__ b){
  __shared__ float red[4];
  const int row = blockIdx.x; const int t = threadIdx.x;
  float v = x[(size_t)row * 256 + t];
  float sv = wave_sum(v);
  if ((t & 63) == 0) red[t >> 6] = sv;
  __syncthreads();
  float mean = (red[0] + red[1] + red[2] + red[3]) * (1.f / 256.f);
  __syncthreads();
  float dv = v - mean;
  float sq = wave_sum(dv * dv);
  if ((t & 63) == 0) red[t >> 6] = sq;
  __syncthreads();
  float var = (red[0] + red[1] + red[2] + red[3]) * (1.f / 256.f);
  float o = dv * rsqrtf(var + 1e-5f) * g[t] + b[t];
  x[(size_t)row * 256 + t] = silu_f(o);
}

// ---------------------------------------------------------------- per-node attention logits
__global__ __launch_bounds__(256) void att_scores_kernel(const float* __restrict__ h, const float* __restrict__ asr,
                                                         const float* __restrict__ adt, float* __restrict__ as_, float* __restrict__ ad_){
  int wid = threadIdx.x >> 6, lane = threadIdx.x & 63;
  int n = blockIdx.x * 4 + wid;
  float s1 = 0.f, s2 = 0.f;
  for (int f = lane; f < 256; f += 64) {
    float hv = h[(size_t)n * 256 + f];
    s1 = fmaf(hv, asr[f], s1); s2 = fmaf(hv, adt[f], s2);
  }
  s1 = wave_sum(s1); s2 = wave_sum(s2);
  if (lane == 0) { as_[n] = s1; ad_[n] = s2; }
}

// ---------------------------------------------------------------- CSR build
__global__ __launch_bounds__(256) void count_kernel(const int* __restrict__ ei, int* __restrict__ cnt_in, int* __restrict__ deg_out){
  int i = blockIdx.x * 256 + threadIdx.x;
  if (i >= ET_) return;
  int dst = (i < E_) ? ei[E_ + i] : (i - E_);
  atomicAdd(&cnt_in[dst], 1);
  if (i < E_) atomicAdd(&deg_out[ei[i]], 1);
}

__global__ __launch_bounds__(1024) void scan_offsets_kernel(const int* __restrict__ cnt, int* __restrict__ off, int* __restrict__ cursor){
  __shared__ int part[1024];
  int t = threadIdx.x;
  int base = t * 16;
  int local[16]; int s = 0;
#pragma unroll
  for (int i = 0; i < 16; ++i) { local[i] = s; s += cnt[base + i]; }
  part[t] = s; __syncthreads();
  for (int d = 1; d < 1024; d <<= 1) {
    int val = part[t];
    int add = (t >= d) ? part[t - d] : 0;
    __syncthreads();
    part[t] = val + add;
    __syncthreads();
  }
  int prev = (t > 0) ? part[t - 1] : 0;
#pragma unroll
  for (int i = 0; i < 16; ++i) { int o = prev + local[i]; off[base + i] = o; cursor[base + i] = o; }
  if (t == 1023) off[N_] = part[1023];
}

__global__ __launch_bounds__(256) void scatter_kernel(const int* __restrict__ ei, int* __restrict__ cursor, int* __restrict__ csr){
  int i = blockIdx.x * 256 + threadIdx.x;
  if (i >= ET_) return;
  int dst = (i < E_) ? ei[E_ + i] : (i - E_);
  int pos = atomicAdd(&cursor[dst], 1);
  csr[pos] = i;
}

// ---------------------------------------------------------------- GAT softmax + aggregate (gather, no float atomics). writes cat[:, :256]
__global__ __launch_bounds__(256) void gat_agg_kernel(const int* __restrict__ ei, const int* __restrict__ off, const int* __restrict__ csr,
                                                      const float* __restrict__ as_, const float* __restrict__ ad_,
                                                      const float* __restrict__ h, const float* __restrict__ gat_b, float* __restrict__ cat){
  const int dst = blockIdx.x;
  const int t = threadIdx.x;
  const int o0 = off[dst];
  int deg = off[dst + 1] - o0;
  if (deg > 1024) deg = 1024;   // cannot occur (mean deg ~17); guards LDS
  __shared__ int   ssrc[1024];
  __shared__ float se[1024];
  __shared__ float red[4];
  const float adv = ad_[dst];
  float m = -1e30f;
  for (int j = t; j < deg; j += 256) {
    int eid = csr[o0 + j];
    int src = (eid < E_) ? ei[eid] : (eid - E_);
    float e = as_[src] + adv;
    e = (e >= 0.f) ? e : 0.2f * e;
    ssrc[j] = src; se[j] = e;
    m = fmaxf(m, e);
  }
  m = wave_max(m);
  if ((t & 63) == 0) red[t >> 6] = m;
  __syncthreads();
  m = fmaxf(fmaxf(red[0], red[1]), fmaxf(red[2], red[3]));
  __syncthreads();
  float dsum = 0.f;
  for (int j = t; j < deg; j += 256) { float x = __expf(se[j] - m); se[j] = x; dsum += x; }
  dsum = wave_sum(dsum);
  if ((t & 63) == 0) red[t >> 6] = dsum;
  __syncthreads();
  float inv = 1.f / (red[0] + red[1] + red[2] + red[3]);
  float acc = gat_b[t];
  for (int j = 0; j < deg; ++j) acc = fmaf(se[j] * inv, h[(size_t)ssrc[j] * 256 + t], acc);
  cat[(size_t)dst * 512 + t] = acc;
}

// ---------------------------------------------------------------- sort key: (enc32(deg + noise*0.1) << 32) | idx
// __fmul_rn/__fadd_rn: forbid FMA contraction so rounding bit-matches the
// reference's separate mul-then-add (near-tie keys decide the mamba ordering).
__global__ __launch_bounds__(256) void key_kernel(const int* __restrict__ degO, const float* __restrict__ noise, unsigned long long* __restrict__ keys){
  int n = blockIdx.x * 256 + threadIdx.x;
  if (n >= N_) return;
  float k = __fadd_rn((float)degO[n], __fmul_rn(noise[n], 0.1f));
  unsigned u = __float_as_uint(k);
  u = (u & 0x80000000u) ? ~u : (u | 0x80000000u);
  keys[n] = ((unsigned long long)u << 32) | (unsigned)n;
}

// ---------------------------------------------------------------- single-block bitonic sort of 16384 u64 keys (== stable argsort)
__global__ __launch_bounds__(1024) void bitonic_kernel(const unsigned long long* __restrict__ keys, int* __restrict__ sidx){
  __shared__ unsigned long long s[N_];
  for (int i = threadIdx.x; i < N_; i += 1024) s[i] = keys[i];
  __syncthreads();
  for (int k = 2; k <= N_; k <<= 1) {
    for (int j = k >> 1; j > 0; j >>= 1) {
      for (int t = threadIdx.x; t < N_ / 2; t += 1024) {
        int i = 2 * t - (t & (j - 1));
        int ixj = i ^ j;
        bool up = ((i & k) == 0);
        unsigned long long a = s[i], b = s[ixj];
        if ((a > b) == up) { s[i] = b; s[ixj] = a; }
      }
      __syncthreads();
    }
  }
  for (int i = threadIdx.x; i < N_; i += 1024) sidx[i] = (int)(s[i] & 0xffffffffu);
}

// ---------------------------------------------------------------- u0 = xf[sidx]
__global__ __launch_bounds__(64) void gather_kernel(const float* __restrict__ xf, const int* __restrict__ sidx, float* __restrict__ u0){
  int i = blockIdx.x, t = threadIdx.x;
  ((float4*)u0)[(size_t)i * 64 + t] = ((const float4*)xf)[(size_t)sidx[i] * 64 + t];
}

// ---------------------------------------------------------------- causal depthwise conv (k=4) + silu; in = xz[:, :512] (stride 1024)
__global__ __launch_bounds__(256) void conv_silu_kernel(const float* __restrict__ xz, const float* __restrict__ cw, float* __restrict__ xm){
  int idx = blockIdx.x * 256 + threadIdx.x;
  if (idx >= N_ * DI_) return;
  int n = idx >> 9, c = idx & 511;
  float acc = 0.f;
#pragma unroll
  for (int k = 0; k < 4; ++k) {
    int nn = n - 3 + k;
    if (nn >= 0) acc = fmaf(xz[(size_t)nn * 1024 + c], cw[c * 4 + k], acc);
  }
  xm[idx] = silu_f(acc);
}

// ================================================================ chunk-parallel selective scan
// recurrence h = exp(Ac*dt)*h + dt*B per (d,s); y[n,d] = sum_s h*B.
// Pass1: per-chunk local scan (h0=0) -> b_final[c,d,s], a_sum[c,d]=Σdt
// Mid  : compose chunks serially -> init[c,d,s]
// Pass3: re-scan chunk from init, emit y.

// staging shared by p1/p3: dt (softplus, fused) and B into LDS
static __device__ __forceinline__ void scan_stage(const float* __restrict__ xdbl,
    const float* __restrict__ dt_w, const float* __restrict__ dt_b,
    int dg, int c, float sdt[CL_][16], float sB[CL_][16])
{
  const int ch = threadIdx.x & 15;
  const int ib = threadIdx.x >> 4;
  const int dch = dg * 16 + ch;
  const float dwv = dt_w[dch], dbv = dt_b[dch];
#pragma unroll
  for (int r = 0; r < CL_ / 16; ++r) {
    int i = ib + r * 16;
    size_t row = (size_t)(c * CL_ + i) * 17;
    float v = fmaf(xdbl[row], dwv, dbv);
    sdt[i][ch] = fmaxf(v, 0.f) + log1pf(__expf(-fabsf(v)));   // softplus
    sB[i][ch]  = xdbl[row + 1 + ch];                          // ch as state idx here
  }
}

__global__ __launch_bounds__(256) void scan_p1_kernel(const float* __restrict__ xdbl,
    const float* __restrict__ dt_w, const float* __restrict__ dt_b, const float* __restrict__ A_log,
    float* __restrict__ a_sum, float* __restrict__ b_final)
{
  const int dg = blockIdx.x;          // channel group (16 ch)
  const int c  = blockIdx.y;          // chunk
  const int dl = threadIdx.x >> 4;
  const int s  = threadIdx.x & 15;
  const int d  = dg * 16 + dl;
  const float Ac = -__expf(A_log[d * 16 + s]);
  __shared__ float sdt[CL_][16];
  __shared__ float sB[CL_][16];
  scan_stage(xdbl, dt_w, dt_b, dg, c, sdt, sB);
  __syncthreads();
  float h = 0.f, dts = 0.f;
#pragma unroll 4
  for (int i = 0; i < CL_; ++i) {
    float dtv = sdt[i][dl];
    float Bv  = sB[i][s];
    h = fmaf(__expf(Ac * dtv), h, dtv * Bv);
    dts += dtv;
  }
  if (s == 0) a_sum[c * 512 + d] = dts;
  b_final[((size_t)c * 512 + d) * 16 + s] = h;
}

__global__ __launch_bounds__(256) void scan_mid_kernel(const float* __restrict__ a_sum,
    const float* __restrict__ b_final, const float* __restrict__ A_log, float* __restrict__ init)
{
  const int d = blockIdx.x * 16 + (threadIdx.x >> 4);
  const int s = threadIdx.x & 15;
  const float Ac = -__expf(A_log[d * 16 + s]);
  float h = 0.f;
  float an = a_sum[d];
  float bn = b_final[(size_t)d * 16 + s];
  for (int c = 0; c < CH_; ++c) {
    float a = an, b = bn;
    if (c + 1 < CH_) {                 // prefetch next chunk's operator
      an = a_sum[(c + 1) * 512 + d];
      bn = b_final[((size_t)(c + 1) * 512 + d) * 16 + s];
    }
    init[((size_t)c * 512 + d) * 16 + s] = h;
    h = fmaf(__expf(Ac * a), h, b);
  }
}

__global__ __launch_bounds__(256) void scan_p3_kernel(const float* __restrict__ xdbl,
    const float* __restrict__ dt_w, const float* __restrict__ dt_b, const float* __restrict__ A_log,
    const float* __restrict__ init, float* __restrict__ ys)   // ys = xz[:, :512], row stride 1024
{
  const int dg = blockIdx.x;
  const int c  = blockIdx.y;
  const int dl = threadIdx.x >> 4;
  const int s  = threadIdx.x & 15;
  const int d  = dg * 16 + dl;
  const float Ac = -__expf(A_log[d * 16 + s]);
  __shared__ float sdt[CL_][16];
  __shared__ float sB[CL_][16];
  scan_stage(xdbl, dt_w, dt_b, dg, c, sdt, sB);
  __syncthreads();
  float h = init[((size_t)c * 512 + d) * 16 + s];
#pragma unroll 4
  for (int i = 0; i < CL_; ++i) {
    float dtv = sdt[i][dl];
    float Bv  = sB[i][s];
    h = fmaf(__expf(Ac * dtv), h, dtv * Bv);
    float p = h * Bv;
    p += __shfl_xor(p, 1); p += __shfl_xor(p, 2); p += __shfl_xor(p, 4); p += __shfl_xor(p, 8);
    if (s == 0) ys[(size_t)(c * CL_ + i) * 1024 + d] = p;
  }
}

// ---------------------------------------------------------------- y = (ys + xm*D) * silu(zgate); ys & zgate live in xz, in place
__global__ __launch_bounds__(256) void ymod_kernel(float* __restrict__ xz, const float* __restrict__ xm,
                                                   const float* __restrict__ Dp){
  int idx = blockIdx.x * 256 + threadIdx.x;
  if (idx >= N_ * DI_) return;
  int n = idx >> 9, c = idx & 511;
  float yv = fmaf(xm[idx], Dp[c], xz[(size_t)n * 1024 + c]);
  float z = xz[(size_t)n * 1024 + 512 + c];
  xz[(size_t)n * 1024 + c] = yv * silu_f(z);
}

// ================================================================ host
extern "C" void kernel_launch(void* const* d_in, const int* in_sizes, int n_in,
                              void* d_out, int out_size, void* d_ws, size_t ws_size,
                              hipStream_t stream)
{
  (void)in_sizes; (void)n_in; (void)out_size;
  const float* x         = (const float*)d_in[0];
  const int*   ei        = (const int*)d_in[1];
  const float* pnoise    = (const float*)d_in[2];
  const float* hop_w     = (const float*)d_in[3];
  const float* hop_b     = (const float*)d_in[4];
  const float* hop_ln_g  = (const float*)d_in[5];
  const float* hop_ln_b  = (const float*)d_in[6];
  const float* gat_w     = (const float*)d_in[7];
  const float* att_src   = (const float*)d_in[8];
  const float* att_dst   = (const float*)d_in[9];
  const float* gat_b     = (const float*)d_in[10];
  const float* in_proj_w = (const float*)d_in[11];
  const float* conv_w    = (const float*)d_in[12];
  const float* x_proj_w  = (const float*)d_in[13];
  const float* dt_w      = (const float*)d_in[14];
  const float* dt_b      = (const float*)d_in[15];
  const float* A_log     = (const float*)d_in[16];
  const float* D_param   = (const float*)d_in[17];
  const float* out_w     = (const float*)d_in[18];
  const float* out_b     = (const float*)d_in[19];
  const float* mlp_w1    = (const float*)d_in[20];
  const float* mlp_b1    = (const float*)d_in[21];
  const float* mlp_ln_g  = (const float*)d_in[22];
  const float* mlp_ln_b  = (const float*)d_in[23];
  const float* mlp_w2    = (const float*)d_in[24];
  const float* mlp_b2    = (const float*)d_in[25];
  float* out = (float*)d_out;

  char* w = (char*)d_ws;
  auto alloc = [&](size_t bytes) -> void* {
    void* p = (void*)w; w += (bytes + 255) & ~(size_t)255; return p;
  };
  // Aliasing plan:
  //   xz  : xcat(N x 768) -> in_proj out(N x 1024); cols[:512] become ys then y
  //   xf  : xf -> mlp1 (xf dead after gather)
  //   h   : h -> u0 (dead after in_proj gemm) -> b_final(4MB) + init(4MB) for scan
  //   csr : dead after gat_agg -> a_sum (256KB)
  float* xz   = (float*)alloc((size_t)N_ * 1024 * 4);  // 64 MiB
  float* xf   = (float*)alloc((size_t)N_ * 256 * 4);   // 16 MiB
  float* h    = (float*)alloc((size_t)N_ * 256 * 4);   // 16 MiB
  float* xm   = (float*)alloc((size_t)N_ * 512 * 4);   // 32 MiB
  float* cat  = (float*)alloc((size_t)N_ * 512 * 4);   // 32 MiB
  float* xdbl = (float*)alloc((size_t)N_ * 17 * 4);
  float* as_  = (float*)alloc((size_t)N_ * 4);
  float* ad_  = (float*)alloc((size_t)N_ * 4);
  int* cnt    = (int*)alloc((size_t)N_ * 4);    // cnt & degO contiguous for one memset
  int* degO   = (int*)alloc((size_t)N_ * 4);
  int* cursor = (int*)alloc((size_t)N_ * 4);
  int* off    = (int*)alloc((size_t)(N_ + 1) * 4);
  int* sidx   = (int*)alloc((size_t)N_ * 4);
  int* csr    = (int*)alloc((size_t)ET_ * 4);
  unsigned long long* keys = (unsigned long long*)alloc((size_t)N_ * 8);
  float* u0      = h;                                    // alias
  float* mlp1    = xf;                                   // alias
  float* b_final = h;                                    // alias (4 MB)
  float* init    = h + (size_t)CH_ * 512 * 16;           // alias (next 4 MB)
  float* a_sum   = (float*)csr;                          // alias (256 KB)
  size_t needed = (size_t)(w - (char*)d_ws);
  if (needed > ws_size) {                    // diagnostic: absmax ~1e9 => ws too small
    marker_kernel<<<1, 256, 0, stream>>>(out);
    return;
  }

  hipMemsetAsync(cnt, 0, 2 * (size_t)N_ * 4, stream);

  // 1. xcat = permute(x)
  permute_kernel<<<(3 * N_ * 64) / 256, 256, 0, stream>>>(x, xz);
  // 2. xf = silu(LN(xcat @ hop_w + hop_b))
  sgemm_kernel<<<dim3(N_ / 64, 4), 256, 0, stream>>>(xz, 768, hop_w, 256, 256, xf, 256, 0, hop_b, nullptr, 768);
  ln_silu_kernel<<<N_, 256, 0, stream>>>(xf, hop_ln_g, hop_ln_b);
  // 3. h = xf @ gat_w
  sgemm_kernel<<<dim3(N_ / 64, 4), 256, 0, stream>>>(xf, 256, gat_w, 256, 256, h, 256, 0, nullptr, nullptr, 256);
  // 4. attention logits per node
  att_scores_kernel<<<N_ / 4, 256, 0, stream>>>(h, att_src, att_dst, as_, ad_);
  // 5. CSR by dst (incl self loops) + out-degree
  count_kernel<<<(ET_ + 255) / 256, 256, 0, stream>>>(ei, cnt, degO);
  scan_offsets_kernel<<<1, 1024, 0, stream>>>(cnt, off, cursor);
  scatter_kernel<<<(ET_ + 255) / 256, 256, 0, stream>>>(ei, cursor, csr);
  // 6. GAT softmax+aggregate -> cat[:, :256]
  gat_agg_kernel<<<N_, 256, 0, stream>>>(ei, off, csr, as_, ad_, h, gat_b, cat);
  // 7. stable argsort(deg + noise*0.1)
  key_kernel<<<N_ / 256, 256, 0, stream>>>(degO, pnoise, keys);
  bitonic_kernel<<<1, 1024, 0, stream>>>(keys, sidx);
  // 8. u0 = xf[sidx]; xz = u0 @ in_proj_w   (overwrites xcat)
  gather_kernel<<<N_, 64, 0, stream>>>(xf, sidx, u0);
  sgemm_kernel<<<dim3(N_ / 64, 16), 256, 0, stream>>>(u0, 256, in_proj_w, 1024, 1024, xz, 1024, 0, nullptr, nullptr, 256);
  // 9. depthwise causal conv + silu -> xm
  conv_silu_kernel<<<(N_ * DI_) / 256, 256, 0, stream>>>(xz, conv_w, xm);
  // 10. x_dbl = xm @ x_proj_w (N=17)
  sgemm_kernel<<<dim3(N_ / 64, 1), 256, 0, stream>>>(xm, 512, x_proj_w, 17, 17, xdbl, 17, 0, nullptr, nullptr, 512);
  // 11+12. chunk-parallel selective scan (dt fused) -> ys = xz[:, :512]
  scan_p1_kernel<<<dim3(32, CH_), 256, 0, stream>>>(xdbl, dt_w, dt_b, A_log, a_sum, b_final);
  scan_mid_kernel<<<32, 256, 0, stream>>>(a_sum, b_final, A_log, init);
  scan_p3_kernel<<<dim3(32, CH_), 256, 0, stream>>>(xdbl, dt_w, dt_b, A_log, init, xz);
  // 13. y = (ys + xm*D) * silu(zgate), in place in xz[:, :512]
  ymod_kernel<<<(N_ * DI_) / 256, 256, 0, stream>>>(xz, xm, D_param);
  // 14. x_mamba = y @ out_w + out_b, scattered (un-permuted) into cat[:, 256:]
  sgemm_kernel<<<dim3(N_ / 64, 4), 256, 0, stream>>>(xz, 1024, out_w, 256, 256, cat, 512, 256, out_b, sidx, 512);
  // 15. MLP
  sgemm_kernel<<<dim3(N_ / 64, 4), 256, 0, stream>>>(cat, 512, mlp_w1, 256, 256, mlp1, 256, 0, mlp_b1, nullptr, 512);
  ln_silu_kernel<<<N_, 256, 0, stream>>>(mlp1, mlp_ln_g, mlp_ln_b);
  sgemm_kernel<<<dim3(N_ / 64, 4), 256, 0, stream>>>(mlp1, 256, mlp_w2, 256, 256, out, 256, 0, mlp_b2, nullptr, 256);
}

// Round 4
// 725.847 us; speedup vs baseline: 5.8528x; 1.3720x over previous
//
#include <hip/hip_runtime.h>

#define N_   16384
#define D_   256
#define E_   262144
#define ET_  278528   // E_ + N_ (self loops)
#define DI_  512
#define CH_  128      // scan chunks
#define CL_  128      // chunk length (CH_*CL_ == N_)

typedef __attribute__((ext_vector_type(8))) short short8;
typedef __attribute__((ext_vector_type(4))) float f32x4;

static __device__ __forceinline__ float wave_sum(float v){
#pragma unroll
  for (int m = 1; m < 64; m <<= 1) v += __shfl_xor(v, m);
  return v;
}
static __device__ __forceinline__ float wave_max(float v){
#pragma unroll
  for (int m = 1; m < 64; m <<= 1) v = fmaxf(v, __shfl_xor(v, m));
  return v;
}
static __device__ __forceinline__ float silu_f(float x){ return x / (1.f + __expf(-x)); }
static __device__ __forceinline__ unsigned short f2b(float f){   // fp32 -> bf16 RNE
  unsigned u = __float_as_uint(f);
  return (unsigned short)((u + 0x7fffu + ((u >> 16) & 1u)) >> 16);
}

// ---------------------------------------------------------------- diagnostic marker (fires only if ws too small)
__global__ __launch_bounds__(256) void marker_kernel(float* __restrict__ out){
  out[threadIdx.x] = 1e9f;
}

// ---------------------------------------------------------------- permute x (3,N,256) -> xcat (N,768)
__global__ __launch_bounds__(256) void permute_kernel(const float* __restrict__ x, float* __restrict__ xcat){
  int idx = blockIdx.x * 256 + threadIdx.x;      // over 3*16384*64 float4
  if (idx >= 3 * N_ * 64) return;
  int d4  = idx & 63;
  int n   = (idx >> 6) & (N_ - 1);
  int hop = idx >> 20;
  float4 v = ((const float4*)x)[((size_t)hop << 20) + ((size_t)n << 6) + d4];
  ((float4*)xcat)[(size_t)n * 192 + hop * 64 + d4] = v;
}

// ---------------------------------------------------------------- weight transpose+convert: W[K x N] fp32 -> BT[Npad x K] bf16
__global__ __launch_bounds__(256) void wconv_kernel(const float* __restrict__ W, int K, int N,
                                                    unsigned short* __restrict__ BT){
  __shared__ float t[32][33];
  const int k0 = blockIdx.x * 32, n0 = blockIdx.y * 32;
  const int tr = threadIdx.x & 31, tc = threadIdx.x >> 5;
#pragma unroll
  for (int r = tc; r < 32; r += 8) {
    int k = k0 + r, n = n0 + tr;
    t[r][tr] = (k < K && n < N) ? W[(size_t)k * N + n] : 0.f;
  }
  __syncthreads();
#pragma unroll
  for (int r = tc; r < 32; r += 8) {
    int n = n0 + r, k = k0 + tr;
    BT[(size_t)n * K + k] = f2b(t[tr][r]);
  }
}

// ---------------------------------------------------------------- bf16 MFMA GEMM
// C[row_map[m], c_off+n] = A(M x K fp32) @ BT^T (BT is [Npad x K] bf16) + bias
// tile 128x64, 4 waves (2x2), per-wave 64x32 = 4x2 frags of 16x16, BK=32.
#define ALD 40   // LDS row stride in bf16 elems (80B): 16B aligned, <=2-way bank conflict
__global__ __launch_bounds__(256) void mgemm_kernel(
    const float* __restrict__ A, int lda,
    const unsigned short* __restrict__ BT, int ldbt, int N,
    float* __restrict__ C, int ldc, int c_off,
    const float* __restrict__ bias, const int* __restrict__ row_map, int K)
{
  __shared__ __align__(16) unsigned short Al[128 * ALD];
  __shared__ __align__(16) unsigned short Bl[64 * ALD];
  const int tid = threadIdx.x;
  const int lane = tid & 63;
  const int wid = tid >> 6;
  const int wr = wid >> 1;           // wave row half (64 rows)
  const int wc = wid & 1;            // wave col half (32 cols)
  const int m0 = blockIdx.x * 128;
  const int n0 = blockIdx.y * 64;
  const int fr = lane & 15, fq = lane >> 4;
  f32x4 acc[4][2] = {};
  for (int k0 = 0; k0 < K; k0 += 32) {
    // stage A: 128x32 fp32 -> bf16 (4 float4 per thread)
#pragma unroll
    for (int i = 0; i < 4; ++i) {
      int f = tid + i * 256;                 // 0..1023
      int r = f >> 3, kq = (f & 7) << 2;
      float4 v = *(const float4*)&A[(size_t)(m0 + r) * lda + k0 + kq];
      unsigned long long pk = (unsigned long long)f2b(v.x)
                            | ((unsigned long long)f2b(v.y) << 16)
                            | ((unsigned long long)f2b(v.z) << 32)
                            | ((unsigned long long)f2b(v.w) << 48);
      *(unsigned long long*)&Al[r * ALD + kq] = pk;
    }
    // stage BT: 64 cols x 32 k bf16 (16B per thread)
    {
      int c = tid >> 2, kq = (tid & 3) << 3;
      short8 v = *(const short8*)&BT[(size_t)(n0 + c) * ldbt + k0 + kq];
      *(short8*)&Bl[c * ALD + kq] = v;
    }
    __syncthreads();
    short8 af[4], bf[2];
#pragma unroll
    for (int m = 0; m < 4; ++m) af[m] = *(const short8*)&Al[(wr * 64 + m * 16 + fr) * ALD + fq * 8];
#pragma unroll
    for (int n = 0; n < 2; ++n) bf[n] = *(const short8*)&Bl[(wc * 32 + n * 16 + fr) * ALD + fq * 8];
#pragma unroll
    for (int n = 0; n < 2; ++n)
#pragma unroll
      for (int m = 0; m < 4; ++m)
        acc[m][n] = __builtin_amdgcn_mfma_f32_16x16x32_bf16(af[m], bf[n], acc[m][n], 0, 0, 0);
    __syncthreads();
  }
  // epilogue: C col=lane&15, row=(lane>>4)*4+j  [m89-verified]
#pragma unroll
  for (int m = 0; m < 4; ++m)
#pragma unroll
    for (int n = 0; n < 2; ++n) {
      int col = n0 + wc * 32 + n * 16 + fr;
      if (col >= N) continue;
      float bv = bias ? bias[col] : 0.f;
#pragma unroll
      for (int j = 0; j < 4; ++j) {
        int row = m0 + wr * 64 + m * 16 + fq * 4 + j;
        int orow = row_map ? row_map[row] : row;
        C[(size_t)orow * ldc + c_off + col] = acc[m][n][j] + bv;
      }
    }
}

// ---------------------------------------------------------------- rowwise LN(256) + silu, in place
__global__ __launch_bounds__(256) void ln_silu_kernel(float* __restrict__ x, const float* __restrict__ g, const float* __restrict__ b){
  __shared__ float red[4];
  const int row = blockIdx.x; const int t = threadIdx.x;
  float v = x[(size_t)row * 256 + t];
  float sv = wave_sum(v);
  if ((t & 63) == 0) red[t >> 6] = sv;
  __syncthreads();
  float mean = (red[0] + red[1] + red[2] + red[3]) * (1.f / 256.f);
  __syncthreads();
  float dv = v - mean;
  float sq = wave_sum(dv * dv);
  if ((t & 63) == 0) red[t >> 6] = sq;
  __syncthreads();
  float var = (red[0] + red[1] + red[2] + red[3]) * (1.f / 256.f);
  float o = dv * rsqrtf(var + 1e-5f) * g[t] + b[t];
  x[(size_t)row * 256 + t] = silu_f(o);
}

// ---------------------------------------------------------------- per-node attention logits
__global__ __launch_bounds__(256) void att_scores_kernel(const float* __restrict__ h, const float* __restrict__ asr,
                                                         const float* __restrict__ adt, float* __restrict__ as_, float* __restrict__ ad_){
  int wid = threadIdx.x >> 6, lane = threadIdx.x & 63;
  int n = blockIdx.x * 4 + wid;
  float s1 = 0.f, s2 = 0.f;
  for (int f = lane; f < 256; f += 64) {
    float hv = h[(size_t)n * 256 + f];
    s1 = fmaf(hv, asr[f], s1); s2 = fmaf(hv, adt[f], s2);
  }
  s1 = wave_sum(s1); s2 = wave_sum(s2);
  if (lane == 0) { as_[n] = s1; ad_[n] = s2; }
}

// ---------------------------------------------------------------- CSR build
__global__ __launch_bounds__(256) void count_kernel(const int* __restrict__ ei, int* __restrict__ cnt_in, int* __restrict__ deg_out){
  int i = blockIdx.x * 256 + threadIdx.x;
  if (i >= ET_) return;
  int dst = (i < E_) ? ei[E_ + i] : (i - E_);
  atomicAdd(&cnt_in[dst], 1);
  if (i < E_) atomicAdd(&deg_out[ei[i]], 1);
}

__global__ __launch_bounds__(1024) void scan_offsets_kernel(const int* __restrict__ cnt, int* __restrict__ off, int* __restrict__ cursor){
  __shared__ int part[1024];
  int t = threadIdx.x;
  int base = t * 16;
  int local[16]; int s = 0;
#pragma unroll
  for (int i = 0; i < 16; ++i) { local[i] = s; s += cnt[base + i]; }
  part[t] = s; __syncthreads();
  for (int d = 1; d < 1024; d <<= 1) {
    int val = part[t];
    int add = (t >= d) ? part[t - d] : 0;
    __syncthreads();
    part[t] = val + add;
    __syncthreads();
  }
  int prev = (t > 0) ? part[t - 1] : 0;
#pragma unroll
  for (int i = 0; i < 16; ++i) { int o = prev + local[i]; off[base + i] = o; cursor[base + i] = o; }
  if (t == 1023) off[N_] = part[1023];
}

__global__ __launch_bounds__(256) void scatter_kernel(const int* __restrict__ ei, int* __restrict__ cursor, int* __restrict__ csr){
  int i = blockIdx.x * 256 + threadIdx.x;
  if (i >= ET_) return;
  int dst = (i < E_) ? ei[E_ + i] : (i - E_);
  int pos = atomicAdd(&cursor[dst], 1);
  csr[pos] = i;
}

// ---------------------------------------------------------------- GAT softmax + aggregate (gather, no float atomics). writes cat[:, :256]
__global__ __launch_bounds__(256) void gat_agg_kernel(const int* __restrict__ ei, const int* __restrict__ off, const int* __restrict__ csr,
                                                      const float* __restrict__ as_, const float* __restrict__ ad_,
                                                      const float* __restrict__ h, const float* __restrict__ gat_b, float* __restrict__ cat){
  const int dst = blockIdx.x;
  const int t = threadIdx.x;
  const int o0 = off[dst];
  int deg = off[dst + 1] - o0;
  if (deg > 1024) deg = 1024;   // cannot occur (mean deg ~17); guards LDS
  __shared__ int   ssrc[1024];
  __shared__ float se[1024];
  __shared__ float red[4];
  const float adv = ad_[dst];
  float m = -1e30f;
  for (int j = t; j < deg; j += 256) {
    int eid = csr[o0 + j];
    int src = (eid < E_) ? ei[eid] : (eid - E_);
    float e = as_[src] + adv;
    e = (e >= 0.f) ? e : 0.2f * e;
    ssrc[j] = src; se[j] = e;
    m = fmaxf(m, e);
  }
  m = wave_max(m);
  if ((t & 63) == 0) red[t >> 6] = m;
  __syncthreads();
  m = fmaxf(fmaxf(red[0], red[1]), fmaxf(red[2], red[3]));
  __syncthreads();
  float dsum = 0.f;
  for (int j = t; j < deg; j += 256) { float x = __expf(se[j] - m); se[j] = x; dsum += x; }
  dsum = wave_sum(dsum);
  if ((t & 63) == 0) red[t >> 6] = dsum;
  __syncthreads();
  float inv = 1.f / (red[0] + red[1] + red[2] + red[3]);
  float acc = gat_b[t];
  for (int j = 0; j < deg; ++j) acc = fmaf(se[j] * inv, h[(size_t)ssrc[j] * 256 + t], acc);
  cat[(size_t)dst * 512 + t] = acc;
}

// ---------------------------------------------------------------- sort key: (enc32(deg + noise*0.1) << 32) | idx
// __fmul_rn/__fadd_rn: forbid FMA contraction so rounding bit-matches the
// reference's separate mul-then-add (near-tie keys decide the mamba ordering).
__global__ __launch_bounds__(256) void key_kernel(const int* __restrict__ degO, const float* __restrict__ noise, unsigned long long* __restrict__ keys){
  int n = blockIdx.x * 256 + threadIdx.x;
  if (n >= N_) return;
  float k = __fadd_rn((float)degO[n], __fmul_rn(noise[n], 0.1f));
  unsigned u = __float_as_uint(k);
  u = (u & 0x80000000u) ? ~u : (u | 0x80000000u);
  keys[n] = ((unsigned long long)u << 32) | (unsigned)n;
}

// ---------------------------------------------------------------- O(N^2) rank sort: keys unique => rank = #{smaller}; sidx[rank]=i
__global__ __launch_bounds__(256) void rank_sort_kernel(const unsigned long long* __restrict__ keys, int* __restrict__ sidx){
  __shared__ unsigned long long tile[2048];
  const int i = blockIdx.x * 256 + threadIdx.x;
  const unsigned long long ki = keys[i];
  int rank = 0;
  for (int base = 0; base < N_; base += 2048) {
    for (int j = threadIdx.x; j < 2048; j += 256) tile[j] = keys[base + j];
    __syncthreads();
#pragma unroll 16
    for (int j = 0; j < 2048; j += 2) {
      rank += (tile[j] < ki);
      rank += (tile[j + 1] < ki);
    }
    __syncthreads();
  }
  sidx[rank] = i;
}

// ---------------------------------------------------------------- u0 = xf[sidx]
__global__ __launch_bounds__(64) void gather_kernel(const float* __restrict__ xf, const int* __restrict__ sidx, float* __restrict__ u0){
  int i = blockIdx.x, t = threadIdx.x;
  ((float4*)u0)[(size_t)i * 64 + t] = ((const float4*)xf)[(size_t)sidx[i] * 64 + t];
}

// ---------------------------------------------------------------- causal depthwise conv (k=4) + silu; in = xz[:, :512] (stride 1024)
__global__ __launch_bounds__(256) void conv_silu_kernel(const float* __restrict__ xz, const float* __restrict__ cw, float* __restrict__ xm){
  int idx = blockIdx.x * 256 + threadIdx.x;
  if (idx >= N_ * DI_) return;
  int n = idx >> 9, c = idx & 511;
  float acc = 0.f;
#pragma unroll
  for (int k = 0; k < 4; ++k) {
    int nn = n - 3 + k;
    if (nn >= 0) acc = fmaf(xz[(size_t)nn * 1024 + c], cw[c * 4 + k], acc);
  }
  xm[idx] = silu_f(acc);
}

// ================================================================ chunk-parallel selective scan
static __device__ __forceinline__ void scan_stage(const float* __restrict__ xdbl,
    const float* __restrict__ dt_w, const float* __restrict__ dt_b,
    int dg, int c, float sdt[CL_][16], float sB[CL_][16])
{
  const int ch = threadIdx.x & 15;
  const int ib = threadIdx.x >> 4;
  const int dch = dg * 16 + ch;
  const float dwv = dt_w[dch], dbv = dt_b[dch];
#pragma unroll
  for (int r = 0; r < CL_ / 16; ++r) {
    int i = ib + r * 16;
    size_t row = (size_t)(c * CL_ + i) * 17;
    float v = fmaf(xdbl[row], dwv, dbv);
    sdt[i][ch] = fmaxf(v, 0.f) + log1pf(__expf(-fabsf(v)));   // softplus
    sB[i][ch]  = xdbl[row + 1 + ch];                          // ch as state idx here
  }
}

__global__ __launch_bounds__(256) void scan_p1_kernel(const float* __restrict__ xdbl,
    const float* __restrict__ dt_w, const float* __restrict__ dt_b, const float* __restrict__ A_log,
    float* __restrict__ a_sum, float* __restrict__ b_final)
{
  const int dg = blockIdx.x;          // channel group (16 ch)
  const int c  = blockIdx.y;          // chunk
  const int dl = threadIdx.x >> 4;
  const int s  = threadIdx.x & 15;
  const int d  = dg * 16 + dl;
  const float Ac = -__expf(A_log[d * 16 + s]);
  __shared__ float sdt[CL_][16];
  __shared__ float sB[CL_][16];
  scan_stage(xdbl, dt_w, dt_b, dg, c, sdt, sB);
  __syncthreads();
  float h = 0.f, dts = 0.f;
#pragma unroll 4
  for (int i = 0; i < CL_; ++i) {
    float dtv = sdt[i][dl];
    float Bv  = sB[i][s];
    h = fmaf(__expf(Ac * dtv), h, dtv * Bv);
    dts += dtv;
  }
  if (s == 0) a_sum[c * 512 + d] = dts;
  b_final[((size_t)c * 512 + d) * 16 + s] = h;
}

__global__ __launch_bounds__(256) void scan_mid_kernel(const float* __restrict__ a_sum,
    const float* __restrict__ b_final, const float* __restrict__ A_log, float* __restrict__ init)
{
  const int d = blockIdx.x * 16 + (threadIdx.x >> 4);
  const int s = threadIdx.x & 15;
  const float Ac = -__expf(A_log[d * 16 + s]);
  float h = 0.f;
  float an = a_sum[d];
  float bn = b_final[(size_t)d * 16 + s];
  for (int c = 0; c < CH_; ++c) {
    float a = an, b = bn;
    if (c + 1 < CH_) {                 // prefetch next chunk's operator
      an = a_sum[(c + 1) * 512 + d];
      bn = b_final[((size_t)(c + 1) * 512 + d) * 16 + s];
    }
    init[((size_t)c * 512 + d) * 16 + s] = h;
    h = fmaf(__expf(Ac * a), h, b);
  }
}

__global__ __launch_bounds__(256) void scan_p3_kernel(const float* __restrict__ xdbl,
    const float* __restrict__ dt_w, const float* __restrict__ dt_b, const float* __restrict__ A_log,
    const float* __restrict__ init, float* __restrict__ ys)   // ys = xz[:, :512], row stride 1024
{
  const int dg = blockIdx.x;
  const int c  = blockIdx.y;
  const int dl = threadIdx.x >> 4;
  const int s  = threadIdx.x & 15;
  const int d  = dg * 16 + dl;
  const float Ac = -__expf(A_log[d * 16 + s]);
  __shared__ float sdt[CL_][16];
  __shared__ float sB[CL_][16];
  scan_stage(xdbl, dt_w, dt_b, dg, c, sdt, sB);
  __syncthreads();
  float h = init[((size_t)c * 512 + d) * 16 + s];
#pragma unroll 4
  for (int i = 0; i < CL_; ++i) {
    float dtv = sdt[i][dl];
    float Bv  = sB[i][s];
    h = fmaf(__expf(Ac * dtv), h, dtv * Bv);
    float p = h * Bv;
    p += __shfl_xor(p, 1); p += __shfl_xor(p, 2); p += __shfl_xor(p, 4); p += __shfl_xor(p, 8);
    if (s == 0) ys[(size_t)(c * CL_ + i) * 1024 + d] = p;
  }
}

// ---------------------------------------------------------------- y = (ys + xm*D) * silu(zgate); ys & zgate live in xz, in place
__global__ __launch_bounds__(256) void ymod_kernel(float* __restrict__ xz, const float* __restrict__ xm,
                                                   const float* __restrict__ Dp){
  int idx = blockIdx.x * 256 + threadIdx.x;
  if (idx >= N_ * DI_) return;
  int n = idx >> 9, c = idx & 511;
  float yv = fmaf(xm[idx], Dp[c], xz[(size_t)n * 1024 + c]);
  float z = xz[(size_t)n * 1024 + 512 + c];
  xz[(size_t)n * 1024 + c] = yv * silu_f(z);
}

// ================================================================ host
extern "C" void kernel_launch(void* const* d_in, const int* in_sizes, int n_in,
                              void* d_out, int out_size, void* d_ws, size_t ws_size,
                              hipStream_t stream)
{
  (void)in_sizes; (void)n_in; (void)out_size;
  const float* x         = (const float*)d_in[0];
  const int*   ei        = (const int*)d_in[1];
  const float* pnoise    = (const float*)d_in[2];
  const float* hop_w     = (const float*)d_in[3];
  const float* hop_b     = (const float*)d_in[4];
  const float* hop_ln_g  = (const float*)d_in[5];
  const float* hop_ln_b  = (const float*)d_in[6];
  const float* gat_w     = (const float*)d_in[7];
  const float* att_src   = (const float*)d_in[8];
  const float* att_dst   = (const float*)d_in[9];
  const float* gat_b     = (const float*)d_in[10];
  const float* in_proj_w = (const float*)d_in[11];
  const float* conv_w    = (const float*)d_in[12];
  const float* x_proj_w  = (const float*)d_in[13];
  const float* dt_w      = (const float*)d_in[14];
  const float* dt_b      = (const float*)d_in[15];
  const float* A_log     = (const float*)d_in[16];
  const float* D_param   = (const float*)d_in[17];
  const float* out_w     = (const float*)d_in[18];
  const float* out_b     = (const float*)d_in[19];
  const float* mlp_w1    = (const float*)d_in[20];
  const float* mlp_b1    = (const float*)d_in[21];
  const float* mlp_ln_g  = (const float*)d_in[22];
  const float* mlp_ln_b  = (const float*)d_in[23];
  const float* mlp_w2    = (const float*)d_in[24];
  const float* mlp_b2    = (const float*)d_in[25];
  float* out = (float*)d_out;

  char* w = (char*)d_ws;
  auto alloc = [&](size_t bytes) -> void* {
    void* p = (void*)w; w += (bytes + 255) & ~(size_t)255; return p;
  };
  float* xz   = (float*)alloc((size_t)N_ * 1024 * 4);  // 64 MiB
  float* xf   = (float*)alloc((size_t)N_ * 256 * 4);   // 16 MiB
  float* h    = (float*)alloc((size_t)N_ * 256 * 4);   // 16 MiB
  float* xm   = (float*)alloc((size_t)N_ * 512 * 4);   // 32 MiB
  float* cat  = (float*)alloc((size_t)N_ * 512 * 4);   // 32 MiB
  float* xdbl = (float*)alloc((size_t)N_ * 17 * 4);
  float* as_  = (float*)alloc((size_t)N_ * 4);
  float* ad_  = (float*)alloc((size_t)N_ * 4);
  int* cnt    = (int*)alloc((size_t)N_ * 4);    // cnt & degO contiguous for one memset
  int* degO   = (int*)alloc((size_t)N_ * 4);
  int* cursor = (int*)alloc((size_t)N_ * 4);
  int* off    = (int*)alloc((size_t)(N_ + 1) * 4);
  int* sidx   = (int*)alloc((size_t)N_ * 4);
  int* csr    = (int*)alloc((size_t)ET_ * 4);
  unsigned long long* keys = (unsigned long long*)alloc((size_t)N_ * 8);
  // bf16 transposed weight panels [Npad x K]
  unsigned short* bt_hop = (unsigned short*)alloc((size_t)256 * 768 * 2);
  unsigned short* bt_gat = (unsigned short*)alloc((size_t)256 * 256 * 2);
  unsigned short* bt_inp = (unsigned short*)alloc((size_t)1024 * 256 * 2);
  unsigned short* bt_xp  = (unsigned short*)alloc((size_t)64 * 512 * 2);
  unsigned short* bt_out = (unsigned short*)alloc((size_t)256 * 512 * 2);
  unsigned short* bt_m1  = (unsigned short*)alloc((size_t)256 * 512 * 2);
  unsigned short* bt_m2  = (unsigned short*)alloc((size_t)256 * 256 * 2);
  float* u0      = h;                                    // alias (h dead after gat_agg)
  float* mlp1    = xf;                                   // alias (xf dead after gather)
  float* b_final = h;                                    // alias (4 MB)
  float* init    = h + (size_t)CH_ * 512 * 16;           // alias (next 4 MB)
  float* a_sum   = (float*)csr;                          // alias (csr dead after gat_agg)
  size_t needed = (size_t)(w - (char*)d_ws);
  if (needed > ws_size) {                    // diagnostic: absmax ~1e9 => ws too small
    marker_kernel<<<1, 256, 0, stream>>>(out);
    return;
  }

  hipMemsetAsync(cnt, 0, 2 * (size_t)N_ * 4, stream);

  // 0. weight panels (bf16, transposed)
  wconv_kernel<<<dim3(24, 8),  256, 0, stream>>>(hop_w,     768, 256,  bt_hop);
  wconv_kernel<<<dim3(8, 8),   256, 0, stream>>>(gat_w,     256, 256,  bt_gat);
  wconv_kernel<<<dim3(8, 32),  256, 0, stream>>>(in_proj_w, 256, 1024, bt_inp);
  wconv_kernel<<<dim3(16, 2),  256, 0, stream>>>(x_proj_w,  512, 17,   bt_xp);
  wconv_kernel<<<dim3(16, 8),  256, 0, stream>>>(out_w,     512, 256,  bt_out);
  wconv_kernel<<<dim3(16, 8),  256, 0, stream>>>(mlp_w1,    512, 256,  bt_m1);
  wconv_kernel<<<dim3(8, 8),   256, 0, stream>>>(mlp_w2,    256, 256,  bt_m2);

  // 1. xcat = permute(x)
  permute_kernel<<<(3 * N_ * 64) / 256, 256, 0, stream>>>(x, xz);
  // 2. xf = silu(LN(xcat @ hop_w + hop_b))
  mgemm_kernel<<<dim3(128, 4), 256, 0, stream>>>(xz, 768, bt_hop, 768, 256, xf, 256, 0, hop_b, nullptr, 768);
  ln_silu_kernel<<<N_, 256, 0, stream>>>(xf, hop_ln_g, hop_ln_b);
  // 3. h = xf @ gat_w
  mgemm_kernel<<<dim3(128, 4), 256, 0, stream>>>(xf, 256, bt_gat, 256, 256, h, 256, 0, nullptr, nullptr, 256);
  // 4. attention logits per node
  att_scores_kernel<<<N_ / 4, 256, 0, stream>>>(h, att_src, att_dst, as_, ad_);
  // 5. CSR by dst (incl self loops) + out-degree
  count_kernel<<<(ET_ + 255) / 256, 256, 0, stream>>>(ei, cnt, degO);
  scan_offsets_kernel<<<1, 1024, 0, stream>>>(cnt, off, cursor);
  scatter_kernel<<<(ET_ + 255) / 256, 256, 0, stream>>>(ei, cursor, csr);
  // 6. GAT softmax+aggregate -> cat[:, :256]
  gat_agg_kernel<<<N_, 256, 0, stream>>>(ei, off, csr, as_, ad_, h, gat_b, cat);
  // 7. stable argsort(deg + noise*0.1)
  key_kernel<<<N_ / 256, 256, 0, stream>>>(degO, pnoise, keys);
  rank_sort_kernel<<<N_ / 256, 256, 0, stream>>>(keys, sidx);
  // 8. u0 = xf[sidx]; xz = u0 @ in_proj_w   (overwrites xcat)
  gather_kernel<<<N_, 64, 0, stream>>>(xf, sidx, u0);
  mgemm_kernel<<<dim3(128, 16), 256, 0, stream>>>(u0, 256, bt_inp, 256, 1024, xz, 1024, 0, nullptr, nullptr, 256);
  // 9. depthwise causal conv + silu -> xm
  conv_silu_kernel<<<(N_ * DI_) / 256, 256, 0, stream>>>(xz, conv_w, xm);
  // 10. x_dbl = xm @ x_proj_w (N=17)
  mgemm_kernel<<<dim3(128, 1), 256, 0, stream>>>(xm, 512, bt_xp, 512, 17, xdbl, 17, 0, nullptr, nullptr, 512);
  // 11+12. chunk-parallel selective scan (dt fused) -> ys = xz[:, :512]
  scan_p1_kernel<<<dim3(32, CH_), 256, 0, stream>>>(xdbl, dt_w, dt_b, A_log, a_sum, b_final);
  scan_mid_kernel<<<32, 256, 0, stream>>>(a_sum, b_final, A_log, init);
  scan_p3_kernel<<<dim3(32, CH_), 256, 0, stream>>>(xdbl, dt_w, dt_b, A_log, init, xz);
  // 13. y = (ys + xm*D) * silu(zgate), in place in xz[:, :512]
  ymod_kernel<<<(N_ * DI_) / 256, 256, 0, stream>>>(xz, xm, D_param);
  // 14. x_mamba = y @ out_w + out_b, scattered (un-permuted) into cat[:, 256:]
  mgemm_kernel<<<dim3(128, 4), 256, 0, stream>>>(xz, 1024, bt_out, 512, 256, cat, 512, 256, out_b, sidx, 512);
  // 15. MLP
  mgemm_kernel<<<dim3(128, 4), 256, 0, stream>>>(cat, 512, bt_m1, 512, 256, mlp1, 256, 0, mlp_b1, nullptr, 512);
  ln_silu_kernel<<<N_, 256, 0, stream>>>(mlp1, mlp_ln_g, mlp_ln_b);
  mgemm_kernel<<<dim3(128, 4), 256, 0, stream>>>(mlp1, 256, bt_m2, 256, 256, out, 256, 0, mlp_b2, nullptr, 256);
}

// Round 5
// 578.601 us; speedup vs baseline: 7.3423x; 1.2545x over previous
//
#include <hip/hip_runtime.h>

#define N_   16384
#define D_   256
#define E_   262144
#define ET_  278528   // E_ + N_ (self loops)
#define DI_  512
#define CH_  128      // scan chunks
#define CL_  128      // chunk length (CH_*CL_ == N_)

typedef __attribute__((ext_vector_type(8))) short short8;
typedef __attribute__((ext_vector_type(4))) float f32x4;

static __device__ __forceinline__ float wave_sum(float v){
#pragma unroll
  for (int m = 1; m < 64; m <<= 1) v += __shfl_xor(v, m);
  return v;
}
static __device__ __forceinline__ float wave_max(float v){
#pragma unroll
  for (int m = 1; m < 64; m <<= 1) v = fmaxf(v, __shfl_xor(v, m));
  return v;
}
static __device__ __forceinline__ float silu_f(float x){ return x / (1.f + __expf(-x)); }
static __device__ __forceinline__ unsigned short f2b(float f){   // fp32 -> bf16 RNE
  unsigned u = __float_as_uint(f);
  return (unsigned short)((u + 0x7fffu + ((u >> 16) & 1u)) >> 16);
}

// ---------------------------------------------------------------- diagnostic marker (fires only if ws too small)
__global__ __launch_bounds__(256) void marker_kernel(float* __restrict__ out){
  out[threadIdx.x] = 1e9f;
}

// ---------------------------------------------------------------- permute x (3,N,256) -> xcat (N,768)
__global__ __launch_bounds__(256) void permute_kernel(const float* __restrict__ x, float* __restrict__ xcat){
  int idx = blockIdx.x * 256 + threadIdx.x;      // over 3*16384*64 float4
  if (idx >= 3 * N_ * 64) return;
  int d4  = idx & 63;
  int n   = (idx >> 6) & (N_ - 1);
  int hop = idx >> 20;
  float4 v = ((const float4*)x)[((size_t)hop << 20) + ((size_t)n << 6) + d4];
  ((float4*)xcat)[(size_t)n * 192 + hop * 64 + d4] = v;
}

// ---------------------------------------------------------------- weight transpose+convert: W[K x N] fp32 -> BT[Npad x K] bf16
__global__ __launch_bounds__(256) void wconv_kernel(const float* __restrict__ W, int K, int N,
                                                    unsigned short* __restrict__ BT){
  __shared__ float t[32][33];
  const int k0 = blockIdx.x * 32, n0 = blockIdx.y * 32;
  const int tr = threadIdx.x & 31, tc = threadIdx.x >> 5;
#pragma unroll
  for (int r = tc; r < 32; r += 8) {
    int k = k0 + r, n = n0 + tr;
    t[r][tr] = (k < K && n < N) ? W[(size_t)k * N + n] : 0.f;
  }
  __syncthreads();
#pragma unroll
  for (int r = tc; r < 32; r += 8) {
    int n = n0 + r, k = k0 + tr;
    BT[(size_t)n * K + k] = f2b(t[tr][r]);
  }
}

// ---------------------------------------------------------------- bf16 MFMA GEMM
// C[row_map[m], c_off+n] = A(M x K fp32) @ BT^T (BT is [Npad x K] bf16) + bias
// tile 128x64, 4 waves (2x2), per-wave 64x32 = 4x2 frags of 16x16, BK=32.
#define ALD 40   // LDS row stride in bf16 elems (80B): 16B aligned, <=2-way bank conflict
__global__ __launch_bounds__(256) void mgemm_kernel(
    const float* __restrict__ A, int lda,
    const unsigned short* __restrict__ BT, int ldbt, int N,
    float* __restrict__ C, int ldc, int c_off,
    const float* __restrict__ bias, const int* __restrict__ row_map, int K)
{
  __shared__ __align__(16) unsigned short Al[128 * ALD];
  __shared__ __align__(16) unsigned short Bl[64 * ALD];
  const int tid = threadIdx.x;
  const int lane = tid & 63;
  const int wid = tid >> 6;
  const int wr = wid >> 1;           // wave row half (64 rows)
  const int wc = wid & 1;            // wave col half (32 cols)
  const int m0 = blockIdx.x * 128;
  const int n0 = blockIdx.y * 64;
  const int fr = lane & 15, fq = lane >> 4;
  f32x4 acc[4][2] = {};
  for (int k0 = 0; k0 < K; k0 += 32) {
    // stage A: 128x32 fp32 -> bf16 (4 float4 per thread)
#pragma unroll
    for (int i = 0; i < 4; ++i) {
      int f = tid + i * 256;                 // 0..1023
      int r = f >> 3, kq = (f & 7) << 2;
      float4 v = *(const float4*)&A[(size_t)(m0 + r) * lda + k0 + kq];
      unsigned long long pk = (unsigned long long)f2b(v.x)
                            | ((unsigned long long)f2b(v.y) << 16)
                            | ((unsigned long long)f2b(v.z) << 32)
                            | ((unsigned long long)f2b(v.w) << 48);
      *(unsigned long long*)&Al[r * ALD + kq] = pk;
    }
    // stage BT: 64 cols x 32 k bf16 (16B per thread)
    {
      int c = tid >> 2, kq = (tid & 3) << 3;
      short8 v = *(const short8*)&BT[(size_t)(n0 + c) * ldbt + k0 + kq];
      *(short8*)&Bl[c * ALD + kq] = v;
    }
    __syncthreads();
    short8 af[4], bf[2];
#pragma unroll
    for (int m = 0; m < 4; ++m) af[m] = *(const short8*)&Al[(wr * 64 + m * 16 + fr) * ALD + fq * 8];
#pragma unroll
    for (int n = 0; n < 2; ++n) bf[n] = *(const short8*)&Bl[(wc * 32 + n * 16 + fr) * ALD + fq * 8];
#pragma unroll
    for (int n = 0; n < 2; ++n)
#pragma unroll
      for (int m = 0; m < 4; ++m)
        acc[m][n] = __builtin_amdgcn_mfma_f32_16x16x32_bf16(af[m], bf[n], acc[m][n], 0, 0, 0);
    __syncthreads();
  }
  // epilogue: C col=lane&15, row=(lane>>4)*4+j  [m89-verified]
#pragma unroll
  for (int m = 0; m < 4; ++m)
#pragma unroll
    for (int n = 0; n < 2; ++n) {
      int col = n0 + wc * 32 + n * 16 + fr;
      if (col >= N) continue;
      float bv = bias ? bias[col] : 0.f;
#pragma unroll
      for (int j = 0; j < 4; ++j) {
        int row = m0 + wr * 64 + m * 16 + fq * 4 + j;
        int orow = row_map ? row_map[row] : row;
        C[(size_t)orow * ldc + c_off + col] = acc[m][n][j] + bv;
      }
    }
}

// ---------------------------------------------------------------- rowwise LN(256) + silu, in place
__global__ __launch_bounds__(256) void ln_silu_kernel(float* __restrict__ x, const float* __restrict__ g, const float* __restrict__ b){
  __shared__ float red[4];
  const int row = blockIdx.x; const int t = threadIdx.x;
  float v = x[(size_t)row * 256 + t];
  float sv = wave_sum(v);
  if ((t & 63) == 0) red[t >> 6] = sv;
  __syncthreads();
  float mean = (red[0] + red[1] + red[2] + red[3]) * (1.f / 256.f);
  __syncthreads();
  float dv = v - mean;
  float sq = wave_sum(dv * dv);
  if ((t & 63) == 0) red[t >> 6] = sq;
  __syncthreads();
  float var = (red[0] + red[1] + red[2] + red[3]) * (1.f / 256.f);
  float o = dv * rsqrtf(var + 1e-5f) * g[t] + b[t];
  x[(size_t)row * 256 + t] = silu_f(o);
}

// ---------------------------------------------------------------- per-node attention logits
__global__ __launch_bounds__(256) void att_scores_kernel(const float* __restrict__ h, const float* __restrict__ asr,
                                                         const float* __restrict__ adt, float* __restrict__ as_, float* __restrict__ ad_){
  int wid = threadIdx.x >> 6, lane = threadIdx.x & 63;
  int n = blockIdx.x * 4 + wid;
  float s1 = 0.f, s2 = 0.f;
  for (int f = lane; f < 256; f += 64) {
    float hv = h[(size_t)n * 256 + f];
    s1 = fmaf(hv, asr[f], s1); s2 = fmaf(hv, adt[f], s2);
  }
  s1 = wave_sum(s1); s2 = wave_sum(s2);
  if (lane == 0) { as_[n] = s1; ad_[n] = s2; }
}

// ---------------------------------------------------------------- CSR build
__global__ __launch_bounds__(256) void count_kernel(const int* __restrict__ ei, int* __restrict__ cnt_in, int* __restrict__ deg_out){
  int i = blockIdx.x * 256 + threadIdx.x;
  if (i >= ET_) return;
  int dst = (i < E_) ? ei[E_ + i] : (i - E_);
  atomicAdd(&cnt_in[dst], 1);
  if (i < E_) atomicAdd(&deg_out[ei[i]], 1);
}

__global__ __launch_bounds__(1024) void scan_offsets_kernel(const int* __restrict__ cnt, int* __restrict__ off, int* __restrict__ cursor){
  __shared__ int part[1024];
  int t = threadIdx.x;
  int base = t * 16;
  int local[16]; int s = 0;
#pragma unroll
  for (int i = 0; i < 16; ++i) { local[i] = s; s += cnt[base + i]; }
  part[t] = s; __syncthreads();
  for (int d = 1; d < 1024; d <<= 1) {
    int val = part[t];
    int add = (t >= d) ? part[t - d] : 0;
    __syncthreads();
    part[t] = val + add;
    __syncthreads();
  }
  int prev = (t > 0) ? part[t - 1] : 0;
#pragma unroll
  for (int i = 0; i < 16; ++i) { int o = prev + local[i]; off[base + i] = o; cursor[base + i] = o; }
  if (t == 1023) off[N_] = part[1023];
}

__global__ __launch_bounds__(256) void scatter_kernel(const int* __restrict__ ei, int* __restrict__ cursor, int* __restrict__ csr){
  int i = blockIdx.x * 256 + threadIdx.x;
  if (i >= ET_) return;
  int dst = (i < E_) ? ei[E_ + i] : (i - E_);
  int pos = atomicAdd(&cursor[dst], 1);
  csr[pos] = i;
}

// ---------------------------------------------------------------- GAT softmax + aggregate (gather, no float atomics). writes cat[:, :256]
__global__ __launch_bounds__(256) void gat_agg_kernel(const int* __restrict__ ei, const int* __restrict__ off, const int* __restrict__ csr,
                                                      const float* __restrict__ as_, const float* __restrict__ ad_,
                                                      const float* __restrict__ h, const float* __restrict__ gat_b, float* __restrict__ cat){
  const int dst = blockIdx.x;
  const int t = threadIdx.x;
  const int o0 = off[dst];
  int deg = off[dst + 1] - o0;
  if (deg > 1024) deg = 1024;   // cannot occur (mean deg ~17); guards LDS
  __shared__ int   ssrc[1024];
  __shared__ float se[1024];
  __shared__ float red[4];
  const float adv = ad_[dst];
  float m = -1e30f;
  for (int j = t; j < deg; j += 256) {
    int eid = csr[o0 + j];
    int src = (eid < E_) ? ei[eid] : (eid - E_);
    float e = as_[src] + adv;
    e = (e >= 0.f) ? e : 0.2f * e;
    ssrc[j] = src; se[j] = e;
    m = fmaxf(m, e);
  }
  m = wave_max(m);
  if ((t & 63) == 0) red[t >> 6] = m;
  __syncthreads();
  m = fmaxf(fmaxf(red[0], red[1]), fmaxf(red[2], red[3]));
  __syncthreads();
  float dsum = 0.f;
  for (int j = t; j < deg; j += 256) { float x = __expf(se[j] - m); se[j] = x; dsum += x; }
  dsum = wave_sum(dsum);
  if ((t & 63) == 0) red[t >> 6] = dsum;
  __syncthreads();
  float inv = 1.f / (red[0] + red[1] + red[2] + red[3]);
  float acc = gat_b[t];
  for (int j = 0; j < deg; ++j) acc = fmaf(se[j] * inv, h[(size_t)ssrc[j] * 256 + t], acc);
  cat[(size_t)dst * 512 + t] = acc;
}

// ---------------------------------------------------------------- sort key: (enc32(deg + noise*0.1) << 32) | idx
// __fmul_rn/__fadd_rn: forbid FMA contraction so rounding bit-matches the
// reference's separate mul-then-add (near-tie keys decide the mamba ordering).
__global__ __launch_bounds__(256) void key_kernel(const int* __restrict__ degO, const float* __restrict__ noise, unsigned long long* __restrict__ keys){
  int n = blockIdx.x * 256 + threadIdx.x;
  if (n >= N_) return;
  float k = __fadd_rn((float)degO[n], __fmul_rn(noise[n], 0.1f));
  unsigned u = __float_as_uint(k);
  u = (u & 0x80000000u) ? ~u : (u | 0x80000000u);
  keys[n] = ((unsigned long long)u << 32) | (unsigned)n;
}

// ---------------------------------------------------------------- O(N^2) rank sort, j-split for occupancy:
// block (bx,by): for 256 i's of bx, count keys < key_i within segment by (512 keys)
__global__ __launch_bounds__(256) void rank_part_kernel(const unsigned long long* __restrict__ keys, int* __restrict__ rank){
  __shared__ unsigned long long tile[512];
  const int i = blockIdx.x * 256 + threadIdx.x;
  const unsigned long long ki = keys[i];
  const int base = blockIdx.y * 512;
  for (int j = threadIdx.x; j < 512; j += 256) tile[j] = keys[base + j];
  __syncthreads();
  int r = 0;
#pragma unroll 16
  for (int j = 0; j < 512; ++j) r += (tile[j] < ki);
  atomicAdd(&rank[i], r);
}
__global__ __launch_bounds__(256) void rank_scatter_kernel(const int* __restrict__ rank, int* __restrict__ sidx){
  int i = blockIdx.x * 256 + threadIdx.x;
  sidx[rank[i]] = i;
}

// ---------------------------------------------------------------- u0 = xf[sidx]
__global__ __launch_bounds__(64) void gather_kernel(const float* __restrict__ xf, const int* __restrict__ sidx, float* __restrict__ u0){
  int i = blockIdx.x, t = threadIdx.x;
  ((float4*)u0)[(size_t)i * 64 + t] = ((const float4*)xf)[(size_t)sidx[i] * 64 + t];
}

// ---------------------------------------------------------------- causal depthwise conv (k=4) + silu; in = xz[:, :512] (stride 1024)
__global__ __launch_bounds__(256) void conv_silu_kernel(const float* __restrict__ xz, const float* __restrict__ cw, float* __restrict__ xm){
  int idx = blockIdx.x * 256 + threadIdx.x;
  if (idx >= N_ * DI_) return;
  int n = idx >> 9, c = idx & 511;
  float acc = 0.f;
#pragma unroll
  for (int k = 0; k < 4; ++k) {
    int nn = n - 3 + k;
    if (nn >= 0) acc = fmaf(xz[(size_t)nn * 1024 + c], cw[c * 4 + k], acc);
  }
  xm[idx] = silu_f(acc);
}

// ================================================================ chunk-parallel selective scan
static __device__ __forceinline__ void scan_stage(const float* __restrict__ xdbl,
    const float* __restrict__ dt_w, const float* __restrict__ dt_b,
    int dg, int c, float sdt[CL_][16], float sB[CL_][16])
{
  const int ch = threadIdx.x & 15;
  const int ib = threadIdx.x >> 4;
  const int dch = dg * 16 + ch;
  const float dwv = dt_w[dch], dbv = dt_b[dch];
#pragma unroll
  for (int r = 0; r < CL_ / 16; ++r) {
    int i = ib + r * 16;
    size_t row = (size_t)(c * CL_ + i) * 17;
    float v = fmaf(xdbl[row], dwv, dbv);
    sdt[i][ch] = fmaxf(v, 0.f) + log1pf(__expf(-fabsf(v)));   // softplus
    sB[i][ch]  = xdbl[row + 1 + ch];                          // ch as state idx here
  }
}

__global__ __launch_bounds__(256) void scan_p1_kernel(const float* __restrict__ xdbl,
    const float* __restrict__ dt_w, const float* __restrict__ dt_b, const float* __restrict__ A_log,
    float* __restrict__ a_sum, float* __restrict__ b_final)
{
  const int dg = blockIdx.x;          // channel group (16 ch)
  const int c  = blockIdx.y;          // chunk
  const int dl = threadIdx.x >> 4;
  const int s  = threadIdx.x & 15;
  const int d  = dg * 16 + dl;
  const float Ac = -__expf(A_log[d * 16 + s]);
  __shared__ float sdt[CL_][16];
  __shared__ float sB[CL_][16];
  scan_stage(xdbl, dt_w, dt_b, dg, c, sdt, sB);
  __syncthreads();
  float h = 0.f, dts = 0.f;
#pragma unroll 4
  for (int i = 0; i < CL_; ++i) {
    float dtv = sdt[i][dl];
    float Bv  = sB[i][s];
    h = fmaf(__expf(Ac * dtv), h, dtv * Bv);
    dts += dtv;
  }
  if (s == 0) a_sum[c * 512 + d] = dts;
  b_final[((size_t)c * 512 + d) * 16 + s] = h;
}

__global__ __launch_bounds__(256) void scan_mid_kernel(const float* __restrict__ a_sum,
    const float* __restrict__ b_final, const float* __restrict__ A_log, float* __restrict__ init)
{
  const int d = blockIdx.x * 16 + (threadIdx.x >> 4);
  const int s = threadIdx.x & 15;
  const float Ac = -__expf(A_log[d * 16 + s]);
  float h = 0.f;
  float an = a_sum[d];
  float bn = b_final[(size_t)d * 16 + s];
  for (int c = 0; c < CH_; ++c) {
    float a = an, b = bn;
    if (c + 1 < CH_) {                 // prefetch next chunk's operator
      an = a_sum[(c + 1) * 512 + d];
      bn = b_final[((size_t)(c + 1) * 512 + d) * 16 + s];
    }
    init[((size_t)c * 512 + d) * 16 + s] = h;
    h = fmaf(__expf(Ac * a), h, b);
  }
}

__global__ __launch_bounds__(256) void scan_p3_kernel(const float* __restrict__ xdbl,
    const float* __restrict__ dt_w, const float* __restrict__ dt_b, const float* __restrict__ A_log,
    const float* __restrict__ init, float* __restrict__ ys)   // ys = xz[:, :512], row stride 1024
{
  const int dg = blockIdx.x;
  const int c  = blockIdx.y;
  const int dl = threadIdx.x >> 4;
  const int s  = threadIdx.x & 15;
  const int d  = dg * 16 + dl;
  const float Ac = -__expf(A_log[d * 16 + s]);
  __shared__ float sdt[CL_][16];
  __shared__ float sB[CL_][16];
  scan_stage(xdbl, dt_w, dt_b, dg, c, sdt, sB);
  __syncthreads();
  float h = init[((size_t)c * 512 + d) * 16 + s];
#pragma unroll 4
  for (int i = 0; i < CL_; ++i) {
    float dtv = sdt[i][dl];
    float Bv  = sB[i][s];
    h = fmaf(__expf(Ac * dtv), h, dtv * Bv);
    float p = h * Bv;
    p += __shfl_xor(p, 1); p += __shfl_xor(p, 2); p += __shfl_xor(p, 4); p += __shfl_xor(p, 8);
    if (s == 0) ys[(size_t)(c * CL_ + i) * 1024 + d] = p;
  }
}

// ---------------------------------------------------------------- y = (ys + xm*D) * silu(zgate); ys & zgate live in xz, in place
__global__ __launch_bounds__(256) void ymod_kernel(float* __restrict__ xz, const float* __restrict__ xm,
                                                   const float* __restrict__ Dp){
  int idx = blockIdx.x * 256 + threadIdx.x;
  if (idx >= N_ * DI_) return;
  int n = idx >> 9, c = idx & 511;
  float yv = fmaf(xm[idx], Dp[c], xz[(size_t)n * 1024 + c]);
  float z = xz[(size_t)n * 1024 + 512 + c];
  xz[(size_t)n * 1024 + c] = yv * silu_f(z);
}

// ================================================================ host
extern "C" void kernel_launch(void* const* d_in, const int* in_sizes, int n_in,
                              void* d_out, int out_size, void* d_ws, size_t ws_size,
                              hipStream_t stream)
{
  (void)in_sizes; (void)n_in; (void)out_size;
  const float* x         = (const float*)d_in[0];
  const int*   ei        = (const int*)d_in[1];
  const float* pnoise    = (const float*)d_in[2];
  const float* hop_w     = (const float*)d_in[3];
  const float* hop_b     = (const float*)d_in[4];
  const float* hop_ln_g  = (const float*)d_in[5];
  const float* hop_ln_b  = (const float*)d_in[6];
  const float* gat_w     = (const float*)d_in[7];
  const float* att_src   = (const float*)d_in[8];
  const float* att_dst   = (const float*)d_in[9];
  const float* gat_b     = (const float*)d_in[10];
  const float* in_proj_w = (const float*)d_in[11];
  const float* conv_w    = (const float*)d_in[12];
  const float* x_proj_w  = (const float*)d_in[13];
  const float* dt_w      = (const float*)d_in[14];
  const float* dt_b      = (const float*)d_in[15];
  const float* A_log     = (const float*)d_in[16];
  const float* D_param   = (const float*)d_in[17];
  const float* out_w     = (const float*)d_in[18];
  const float* out_b     = (const float*)d_in[19];
  const float* mlp_w1    = (const float*)d_in[20];
  const float* mlp_b1    = (const float*)d_in[21];
  const float* mlp_ln_g  = (const float*)d_in[22];
  const float* mlp_ln_b  = (const float*)d_in[23];
  const float* mlp_w2    = (const float*)d_in[24];
  const float* mlp_b2    = (const float*)d_in[25];
  float* out = (float*)d_out;

  char* w = (char*)d_ws;
  auto alloc = [&](size_t bytes) -> void* {
    void* p = (void*)w; w += (bytes + 255) & ~(size_t)255; return p;
  };
  float* xz   = (float*)alloc((size_t)N_ * 1024 * 4);  // 64 MiB
  float* xf   = (float*)alloc((size_t)N_ * 256 * 4);   // 16 MiB
  float* h    = (float*)alloc((size_t)N_ * 256 * 4);   // 16 MiB
  float* xm   = (float*)alloc((size_t)N_ * 512 * 4);   // 32 MiB
  float* cat  = (float*)alloc((size_t)N_ * 512 * 4);   // 32 MiB
  float* xdbl = (float*)alloc((size_t)N_ * 17 * 4);
  float* as_  = (float*)alloc((size_t)N_ * 4);
  float* ad_  = (float*)alloc((size_t)N_ * 4);
  int* cnt    = (int*)alloc((size_t)N_ * 4);    // cnt, degO, rank contiguous for one memset
  int* degO   = (int*)alloc((size_t)N_ * 4);
  int* rank   = (int*)alloc((size_t)N_ * 4);
  int* cursor = (int*)alloc((size_t)N_ * 4);
  int* off    = (int*)alloc((size_t)(N_ + 1) * 4);
  int* sidx   = (int*)alloc((size_t)N_ * 4);
  int* csr    = (int*)alloc((size_t)ET_ * 4);
  unsigned long long* keys = (unsigned long long*)alloc((size_t)N_ * 8);
  // bf16 transposed weight panels [Npad x K]
  unsigned short* bt_hop = (unsigned short*)alloc((size_t)256 * 768 * 2);
  unsigned short* bt_gat = (unsigned short*)alloc((size_t)256 * 256 * 2);
  unsigned short* bt_inp = (unsigned short*)alloc((size_t)1024 * 256 * 2);
  unsigned short* bt_xp  = (unsigned short*)alloc((size_t)64 * 512 * 2);
  unsigned short* bt_out = (unsigned short*)alloc((size_t)256 * 512 * 2);
  unsigned short* bt_m1  = (unsigned short*)alloc((size_t)256 * 512 * 2);
  unsigned short* bt_m2  = (unsigned short*)alloc((size_t)256 * 256 * 2);
  float* u0      = h;                                    // alias (h dead after gat_agg)
  float* mlp1    = xf;                                   // alias (xf dead after gather)
  float* b_final = h;                                    // alias (4 MB)
  float* init    = h + (size_t)CH_ * 512 * 16;           // alias (next 4 MB)
  float* a_sum   = (float*)csr;                          // alias (csr dead after gat_agg)
  size_t needed = (size_t)(w - (char*)d_ws);
  if (needed > ws_size) {                    // diagnostic: absmax ~1e9 => ws too small
    marker_kernel<<<1, 256, 0, stream>>>(out);
    return;
  }

  hipMemsetAsync(cnt, 0, 3 * (size_t)N_ * 4, stream);   // cnt + degO + rank

  // 0. weight panels (bf16, transposed)
  wconv_kernel<<<dim3(24, 8),  256, 0, stream>>>(hop_w,     768, 256,  bt_hop);
  wconv_kernel<<<dim3(8, 8),   256, 0, stream>>>(gat_w,     256, 256,  bt_gat);
  wconv_kernel<<<dim3(8, 32),  256, 0, stream>>>(in_proj_w, 256, 1024, bt_inp);
  wconv_kernel<<<dim3(16, 2),  256, 0, stream>>>(x_proj_w,  512, 17,   bt_xp);
  wconv_kernel<<<dim3(16, 8),  256, 0, stream>>>(out_w,     512, 256,  bt_out);
  wconv_kernel<<<dim3(16, 8),  256, 0, stream>>>(mlp_w1,    512, 256,  bt_m1);
  wconv_kernel<<<dim3(8, 8),   256, 0, stream>>>(mlp_w2,    256, 256,  bt_m2);

  // 1. xcat = permute(x)
  permute_kernel<<<(3 * N_ * 64) / 256, 256, 0, stream>>>(x, xz);
  // 2. xf = silu(LN(xcat @ hop_w + hop_b))
  mgemm_kernel<<<dim3(128, 4), 256, 0, stream>>>(xz, 768, bt_hop, 768, 256, xf, 256, 0, hop_b, nullptr, 768);
  ln_silu_kernel<<<N_, 256, 0, stream>>>(xf, hop_ln_g, hop_ln_b);
  // 3. h = xf @ gat_w
  mgemm_kernel<<<dim3(128, 4), 256, 0, stream>>>(xf, 256, bt_gat, 256, 256, h, 256, 0, nullptr, nullptr, 256);
  // 4. attention logits per node
  att_scores_kernel<<<N_ / 4, 256, 0, stream>>>(h, att_src, att_dst, as_, ad_);
  // 5. CSR by dst (incl self loops) + out-degree
  count_kernel<<<(ET_ + 255) / 256, 256, 0, stream>>>(ei, cnt, degO);
  scan_offsets_kernel<<<1, 1024, 0, stream>>>(cnt, off, cursor);
  scatter_kernel<<<(ET_ + 255) / 256, 256, 0, stream>>>(ei, cursor, csr);
  // 6. GAT softmax+aggregate -> cat[:, :256]
  gat_agg_kernel<<<N_, 256, 0, stream>>>(ei, off, csr, as_, ad_, h, gat_b, cat);
  // 7. stable argsort(deg + noise*0.1): rank reduction split over 32 j-segments
  key_kernel<<<N_ / 256, 256, 0, stream>>>(degO, pnoise, keys);
  rank_part_kernel<<<dim3(N_ / 256, 32), 256, 0, stream>>>(keys, rank);
  rank_scatter_kernel<<<N_ / 256, 256, 0, stream>>>(rank, sidx);
  // 8. u0 = xf[sidx]; xz = u0 @ in_proj_w   (overwrites xcat)
  gather_kernel<<<N_, 64, 0, stream>>>(xf, sidx, u0);
  mgemm_kernel<<<dim3(128, 16), 256, 0, stream>>>(u0, 256, bt_inp, 256, 1024, xz, 1024, 0, nullptr, nullptr, 256);
  // 9. depthwise causal conv + silu -> xm
  conv_silu_kernel<<<(N_ * DI_) / 256, 256, 0, stream>>>(xz, conv_w, xm);
  // 10. x_dbl = xm @ x_proj_w (N=17)
  mgemm_kernel<<<dim3(128, 1), 256, 0, stream>>>(xm, 512, bt_xp, 512, 17, xdbl, 17, 0, nullptr, nullptr, 512);
  // 11+12. chunk-parallel selective scan (dt fused) -> ys = xz[:, :512]
  scan_p1_kernel<<<dim3(32, CH_), 256, 0, stream>>>(xdbl, dt_w, dt_b, A_log, a_sum, b_final);
  scan_mid_kernel<<<32, 256, 0, stream>>>(a_sum, b_final, A_log, init);
  scan_p3_kernel<<<dim3(32, CH_), 256, 0, stream>>>(xdbl, dt_w, dt_b, A_log, init, xz);
  // 13. y = (ys + xm*D) * silu(zgate), in place in xz[:, :512]
  ymod_kernel<<<(N_ * DI_) / 256, 256, 0, stream>>>(xz, xm, D_param);
  // 14. x_mamba = y @ out_w + out_b, scattered (un-permuted) into cat[:, 256:]
  mgemm_kernel<<<dim3(128, 4), 256, 0, stream>>>(xz, 1024, bt_out, 512, 256, cat, 512, 256, out_b, sidx, 512);
  // 15. MLP
  mgemm_kernel<<<dim3(128, 4), 256, 0, stream>>>(cat, 512, bt_m1, 512, 256, mlp1, 256, 0, mlp_b1, nullptr, 512);
  ln_silu_kernel<<<N_, 256, 0, stream>>>(mlp1, mlp_ln_g, mlp_ln_b);
  mgemm_kernel<<<dim3(128, 4), 256, 0, stream>>>(mlp1, 256, bt_m2, 256, 256, out, 256, 0, mlp_b2, nullptr, 256);
}